// Round 4
// baseline (1092.754 us; speedup 1.0000x reference)
//
#include <hip/hip_runtime.h>
#include <math.h>

// Problem constants
#define NB    8192          // N
#define FEAT  255
#define HID   64
#define TOPK  6000
#define POSTK 300
#define BINS  8192          // 13-bit sortable-float key bins (sign+8exp+4mant)
#define BSHIFT 19           // 32-13
#define CAP   131072        // candidate buffer capacity
#define CAPLIM 98304        // target upper bound on estimated candidate count
#define SLACK 2             // extra bins below threshold bin (absorbs f32 vs f64 noise)
#define TSEL  2000          // sampled cnt_ge target (1/8 col sample, => true ~16000)
#define JSLICES 64          // j-dimension parallelism for rank counting

__device__ __forceinline__ unsigned binOf(float x) {
    unsigned u = __float_as_uint(x);
    u = (u & 0x80000000u) ? ~u : (u | 0x80000000u);   // sortable key (ascending)
    return u >> BSHIFT;
}

// ---------------------------------------------------------------------------
// K1: the two 255->64->64 MLPs in f64. One block = 4 rows, 64 threads/row.
// Writes row-major f64 (for candidate refine) and transposed f32 [k][n].
// ---------------------------------------------------------------------------
__global__ __launch_bounds__(256) void mlp_kernel(
    const float* __restrict__ feat,
    const float* __restrict__ W1s, const float* __restrict__ b1s,
    const float* __restrict__ W2s, const float* __restrict__ b2s,
    const float* __restrict__ W1o, const float* __restrict__ b1o,
    const float* __restrict__ W2o, const float* __restrict__ b2o,
    double* __restrict__ Xs64, double* __restrict__ Xo64,
    float* __restrict__ XsT, float* __restrict__ XoT)
{
    int tid  = threadIdx.x;
    int trow = tid >> 6;          // 0..3
    int t    = tid & 63;          // hidden unit
    int r    = blockIdx.x * 4 + trow;
    __shared__ double hs[4][64];
    __shared__ double ho[4][64];

    const float* frow = feat + (size_t)r * FEAT;
    double as = (double)b1s[t];
    double ao = (double)b1o[t];
    for (int k = 0; k < FEAT; ++k) {
        double fv = (double)frow[k];
        as += fv * (double)W1s[k * HID + t];
        ao += fv * (double)W1o[k * HID + t];
    }
    hs[trow][t] = as > 0.0 ? as : 0.0;
    ho[trow][t] = ao > 0.0 ? ao : 0.0;
    __syncthreads();

    double xs = (double)b2s[t];
    double xo = (double)b2o[t];
    for (int k = 0; k < HID; ++k) {
        xs += hs[trow][k] * (double)W2s[k * HID + t];
        xo += ho[trow][k] * (double)W2o[k * HID + t];
    }
    size_t o = (size_t)r * HID + t;
    Xs64[o] = xs;
    Xo64[o] = xo;
    XsT[(size_t)t * NB + r] = (float)xs;   // [k][n] layout for coalesced GEMM
    XoT[(size_t)t * NB + r] = (float)xo;
}

// ---------------------------------------------------------------------------
// K2: pass A — f32 logits for a 1/8 COLUMN SAMPLE (cols 0..1023).
// 128x128 tile / block, 256 threads x (8x8 micro-tile). Histogram of
// sortable keys in LDS, merged into global histogram. Sample is a strict
// subset of the population, so cnt_ge(sampled) <= cnt_ge(true) always.
// ---------------------------------------------------------------------------
__global__ __launch_bounds__(256, 2) void scores_pass_a(
    const float* __restrict__ XsT, const float* __restrict__ XoT,
    unsigned* __restrict__ ghist)
{
    __shared__ unsigned hist[BINS];   // 32 KB
    int tid = threadIdx.x;
    for (int i = tid; i < BINS; i += 256) hist[i] = 0u;
    __syncthreads();

    int tr = tid >> 4, tc = tid & 15;
    int r0 = blockIdx.y * 128 + tr * 8;
    int c0 = blockIdx.x * 128 + tc * 8;   // gridDim.x = 8 -> cols 0..1023

    float acc[8][8];
#pragma unroll
    for (int i = 0; i < 8; ++i)
#pragma unroll
        for (int j = 0; j < 8; ++j) acc[i][j] = 0.0f;

#pragma unroll 2
    for (int k = 0; k < HID; ++k) {
        const float4* ap = (const float4*)(XsT + (size_t)k * NB + r0);
        const float4* bp = (const float4*)(XoT + (size_t)k * NB + c0);
        float4 a0 = ap[0], a1 = ap[1];
        float4 b0 = bp[0], b1 = bp[1];
        float a[8] = {a0.x, a0.y, a0.z, a0.w, a1.x, a1.y, a1.z, a1.w};
        float b[8] = {b0.x, b0.y, b0.z, b0.w, b1.x, b1.y, b1.z, b1.w};
#pragma unroll
        for (int i = 0; i < 8; ++i)
#pragma unroll
            for (int j = 0; j < 8; ++j)
                acc[i][j] = fmaf(a[i], b[j], acc[i][j]);
    }

#pragma unroll
    for (int i = 0; i < 8; ++i)
#pragma unroll
        for (int j = 0; j < 8; ++j) {
            float v = acc[i][j];
            if (r0 + i == c0 + j) v = -1.0f;      // diagonal, like reference
            atomicAdd(&hist[binOf(v)], 1u);
        }

    __syncthreads();
    for (int i = tid; i < BINS; i += 256) {
        unsigned h = hist[i];
        if (h) atomicAdd(&ghist[i], h);
    }
}

// ---------------------------------------------------------------------------
// K3: from the SAMPLED histogram find bstar = largest bin with
// cnt_ge >= TSEL (=> true cnt_ge >= 6000 w.h.p. and >= sampled count hard),
// lower by SLACK bins for f32-vs-f64 noise, then walk up while the x8
// extrapolated candidate count exceeds CAPLIM.
// ---------------------------------------------------------------------------
__global__ __launch_bounds__(256) void find_threshold(
    const unsigned* __restrict__ ghist, unsigned* __restrict__ ctrl)
{
    __shared__ unsigned csum[256];
    int tid  = threadIdx.x;
    int base = tid * (BINS / 256);
    unsigned s = 0;
    for (int i = 0; i < BINS / 256; ++i) s += ghist[base + i];
    csum[tid] = s;
    __syncthreads();
    if (tid == 0) {                       // suffix sums of chunk totals
        unsigned run = 0;
        for (int c = 255; c >= 0; --c) { run += csum[c]; csum[c] = run; }
    }
    __syncthreads();

    unsigned above = (tid == 255) ? 0u : csum[tid + 1];  // cnt_ge[chunk end]
    unsigned prev = above;
    for (int b = base + BINS / 256 - 1; b >= base; --b) {
        unsigned cur = prev + ghist[b];
        if (cur >= TSEL && prev < TSEL) {
            unsigned bstar = (unsigned)b;
            unsigned bt = bstar >= SLACK ? bstar - SLACK : 0;
            unsigned cnt = cur;
            for (unsigned bb = bstar; bb-- > bt;) cnt += ghist[bb];
            while (8u * cnt > CAPLIM && bt < bstar) { cnt -= ghist[bt]; bt++; }
            ctrl[1] = bt;
            break;
        }
        prev = cur;
    }
}

// ---------------------------------------------------------------------------
// K4: pass B — full f32 GEMM; elements whose f32 bin clears the threshold
// get an exact f64 dot (same sequential-k accumulation order everywhere)
// and are compacted into the candidate buffer.
// ---------------------------------------------------------------------------
__global__ __launch_bounds__(256, 2) void scores_pass_b(
    const float* __restrict__ XsT, const float* __restrict__ XoT,
    const double* __restrict__ Xs64, const double* __restrict__ Xo64,
    unsigned* __restrict__ ctrl,
    double* __restrict__ cval, unsigned* __restrict__ cidx)
{
    unsigned bt = ctrl[1];
    int tid = threadIdx.x;
    int tr = tid >> 4, tc = tid & 15;
    int r0 = blockIdx.y * 128 + tr * 8;
    int c0 = blockIdx.x * 128 + tc * 8;

    float acc[8][8];
#pragma unroll
    for (int i = 0; i < 8; ++i)
#pragma unroll
        for (int j = 0; j < 8; ++j) acc[i][j] = 0.0f;

#pragma unroll 2
    for (int k = 0; k < HID; ++k) {
        const float4* ap = (const float4*)(XsT + (size_t)k * NB + r0);
        const float4* bp = (const float4*)(XoT + (size_t)k * NB + c0);
        float4 a0 = ap[0], a1 = ap[1];
        float4 b0 = bp[0], b1 = bp[1];
        float a[8] = {a0.x, a0.y, a0.z, a0.w, a1.x, a1.y, a1.z, a1.w};
        float b[8] = {b0.x, b0.y, b0.z, b0.w, b1.x, b1.y, b1.z, b1.w};
#pragma unroll
        for (int i = 0; i < 8; ++i)
#pragma unroll
            for (int j = 0; j < 8; ++j)
                acc[i][j] = fmaf(a[i], b[j], acc[i][j]);
    }

#pragma unroll
    for (int i = 0; i < 8; ++i)
#pragma unroll
        for (int j = 0; j < 8; ++j) {
            int r = r0 + i, c = c0 + j;
            float v = acc[i][j];
            if (r == c) v = -1.0f;
            if (binOf(v) >= bt) {
                // exact f64 refine (rare path)
                double vd;
                if (r == c) {
                    vd = -1.0;
                } else {
                    const double* As = Xs64 + (size_t)r * HID;
                    const double* Bs = Xo64 + (size_t)c * HID;
                    vd = 0.0;
#pragma unroll 8
                    for (int k = 0; k < HID; ++k)
                        vd = fma(As[k], Bs[k], vd);
                }
                unsigned p = atomicAdd(&ctrl[0], 1u);
                if (p < CAP) {
                    cval[p] = vd;
                    cidx[p] = (unsigned)r * (unsigned)NB + (unsigned)c;
                }
            }
        }
}

// ---------------------------------------------------------------------------
// K5a: rank-by-counting, 2-D parallel. Grid (i_tile, j_slice). Each block
// counts its 256 candidates against one j-slice (LDS-staged 256 at a time)
// and atomically accumulates into rank[]. Composite key: value desc, flat
// index asc (jax top_k tie-break).
// ---------------------------------------------------------------------------
__global__ __launch_bounds__(256) void rank_count(
    const unsigned* __restrict__ ctrl,
    const double* __restrict__ cval, const unsigned* __restrict__ cidx,
    unsigned* __restrict__ rank)
{
    unsigned M = ctrl[0];
    if (M > CAP) M = CAP;
    unsigned itile = blockIdx.x;
    if (itile * 256u >= M) return;

    unsigned t = itile * 256u + threadIdx.x;
    bool act = t < M;
    double v  = act ? cval[t] : 0.0;
    unsigned id = act ? cidx[t] : 0u;
    unsigned cnt = 0;

    // j-slice range
    unsigned slice = blockIdx.y;
    unsigned jbeg = (unsigned)(((unsigned long long)slice * M) / JSLICES);
    unsigned jend = (unsigned)(((unsigned long long)(slice + 1) * M) / JSLICES);

    __shared__ double  lv[256];
    __shared__ unsigned li[256];
    for (unsigned base = jbeg; base < jend; base += 256u) {
        unsigned j = base + threadIdx.x;
        if (j < jend) { lv[threadIdx.x] = cval[j]; li[threadIdx.x] = cidx[j]; }
        __syncthreads();
        unsigned lim = jend - base; if (lim > 256u) lim = 256u;
        if (act) {
            for (unsigned e = 0; e < lim; ++e) {
                double ev = lv[e];
                cnt += (ev > v) || (ev == v && li[e] < id);
            }
        }
        __syncthreads();
    }
    if (act && cnt) atomicAdd(&rank[t], cnt);
}

// ---------------------------------------------------------------------------
// K5b: scatter candidates with rank < TOPK into sorted arrays.
// ---------------------------------------------------------------------------
__global__ __launch_bounds__(256) void rank_scatter(
    const unsigned* __restrict__ ctrl,
    const double* __restrict__ cval, const unsigned* __restrict__ cidx,
    const unsigned* __restrict__ rank,
    double* __restrict__ sval, unsigned* __restrict__ sidx)
{
    unsigned M = ctrl[0];
    if (M > CAP) M = CAP;
    unsigned t = blockIdx.x * 256u + threadIdx.x;
    if (t >= M) return;
    unsigned r = rank[t];
    if (r < TOPK) { sval[r] = cval[t]; sidx[r] = cidx[t]; }
}

// ---------------------------------------------------------------------------
// K6: union boxes + 0.7*area for the sorted TOPK pairs.
// ---------------------------------------------------------------------------
__global__ __launch_bounds__(256) void nms_prep(
    const unsigned* __restrict__ sidx, const float* __restrict__ rois,
    double* __restrict__ ub)
{
    int t = blockIdx.x * 256 + threadIdx.x;
    if (t >= TOPK) return;
    unsigned id = sidx[t];
    unsigned s = id >> 13, o = id & (NB - 1);
    const float* bs = rois + (size_t)s * 5;
    const float* bo = rois + (size_t)o * 5;
    double x1 = fmin((double)bs[1], (double)bo[1]);
    double y1 = fmin((double)bs[2], (double)bo[2]);
    double x2 = fmax((double)bs[3], (double)bo[3]);
    double y2 = fmax((double)bs[4], (double)bo[4]);
    double area = (x2 - x1) * (y2 - y1);
    double* u = ub + (size_t)t * 5;
    u[0] = x1; u[1] = y1; u[2] = x2; u[3] = y2; u[4] = 0.7 * area;
}

// ---------------------------------------------------------------------------
// K7: suppressed[j] = OR_{i<j} (iou > 0.7). Division-free equivalent:
// inter/(ai+aj-inter+1e-8) > 0.7  <=>  1.7*inter > 0.7*ai + 0.7*aj + 7e-9.
// Grid (jb, ib) tiles of 256x256 pairs.
// ---------------------------------------------------------------------------
__global__ __launch_bounds__(256) void nms_kernel(
    const double* __restrict__ ub, unsigned* __restrict__ sup)
{
    int jb = blockIdx.x, ib = blockIdx.y;
    if (ib > jb) return;
    __shared__ double L[256][5];
    int tid = threadIdx.x;
    int ibase = ib * 256;
    int icount = TOPK - ibase; if (icount > 256) icount = 256;
    if (tid < icount) {
        const double* u = ub + (size_t)(ibase + tid) * 5;
#pragma unroll
        for (int q = 0; q < 5; ++q) L[tid][q] = u[q];
    }
    __syncthreads();

    int j = jb * 256 + tid;
    if (j >= TOPK) return;
    const double* u = ub + (size_t)j * 5;
    double x1 = u[0], y1 = u[1], x2 = u[2], y2 = u[3], pa = u[4];
    int lim = j - ibase; if (lim > icount) lim = icount;  // i < j
    bool flag = false;
    for (int e = 0; e < lim; ++e) {
        double ix1 = fmax(L[e][0], x1);
        double iy1 = fmax(L[e][1], y1);
        double ix2 = fmin(L[e][2], x2);
        double iy2 = fmin(L[e][3], y2);
        double iw = ix2 - ix1; iw = iw > 0.0 ? iw : 0.0;
        double ih = iy2 - iy1; ih = ih > 0.0 ? ih : 0.0;
        double inter = iw * ih;
        if (1.7 * inter > pa + L[e][4] + 7e-9) { flag = true; break; }
    }
    if (flag) atomicOr(&sup[j], 1u);
}

// ---------------------------------------------------------------------------
// K8: top-300 of where(sup,-1,score) over the descending-sorted list is a
// stable partition (unsuppressed first, then suppressed with score -1).
// Single block, chunked LDS scan. Writes all 900 output floats.
// ---------------------------------------------------------------------------
__global__ __launch_bounds__(1024) void finalize_kernel(
    const unsigned* __restrict__ sup, const double* __restrict__ sval,
    const unsigned* __restrict__ sidx, float* __restrict__ out)
{
    __shared__ unsigned pref[1024];
    __shared__ unsigned bases[2];   // running {unsup, sup} counts
    __shared__ unsigned totalu;
    int tid = threadIdx.x;

    unsigned s = 0;
    for (int i = tid; i < TOPK; i += 1024) s += (sup[i] == 0u);
    pref[tid] = s;
    __syncthreads();
    for (int st = 512; st > 0; st >>= 1) {
        if (tid < st) pref[tid] += pref[tid + st];
        __syncthreads();
    }
    if (tid == 0) { totalu = pref[0]; bases[0] = 0; bases[1] = 0; }
    __syncthreads();

    for (int c = 0; c < (TOPK + 1023) / 1024; ++c) {
        int idx = c * 1024 + tid;
        int valid = TOPK - c * 1024; if (valid > 1024) valid = 1024;
        unsigned f = (idx < TOPK && sup[idx] == 0u) ? 1u : 0u;
        pref[tid] = f;
        __syncthreads();
        for (int st = 1; st < 1024; st <<= 1) {
            unsigned add = (tid >= st) ? pref[tid - st] : 0u;
            __syncthreads();
            pref[tid] += add;
            __syncthreads();
        }
        if (idx < TOPK) {
            unsigned incl = pref[tid];
            unsigned e = incl - f;                     // unsup before me in chunk
            unsigned pos = f ? (bases[0] + e)
                             : (totalu + bases[1] + (unsigned)tid - e);
            if (pos < POSTK) {
                unsigned id = sidx[idx];
                unsigned sb = id >> 13, ob = id & (NB - 1);
                out[2 * pos]     = (float)sb;
                out[2 * pos + 1] = (float)ob;
                double sg = f ? 1.0 / (1.0 + exp(-sval[idx])) : -1.0;
                out[2 * POSTK + pos] = (float)sg;
            }
        }
        __syncthreads();
        if (tid == 0) {
            unsigned inclLast = pref[valid - 1];
            bases[0] += inclLast;
            bases[1] += (unsigned)valid - inclLast;
        }
        __syncthreads();
    }
}

// ---------------------------------------------------------------------------
extern "C" void kernel_launch(void* const* d_in, const int* in_sizes, int n_in,
                              void* d_out, int out_size, void* d_ws, size_t ws_size,
                              hipStream_t stream)
{
    const float* rois = (const float*)d_in[0];
    const float* feat = (const float*)d_in[1];
    const float* W1s  = (const float*)d_in[2];
    const float* b1s  = (const float*)d_in[3];
    const float* W2s  = (const float*)d_in[4];
    const float* b2s  = (const float*)d_in[5];
    const float* W1o  = (const float*)d_in[6];
    const float* b1o  = (const float*)d_in[7];
    const float* W2o  = (const float*)d_in[8];
    const float* b2o  = (const float*)d_in[9];

    char* ws = (char*)d_ws;
    size_t off = 0;
    auto alloc = [&](size_t bytes) -> void* {
        off = (off + 255) & ~(size_t)255;
        void* p = ws + off;
        off += bytes;
        return p;
    };

    // zeroed region first
    unsigned* ghist = (unsigned*)alloc((size_t)BINS * 4);     // histogram
    unsigned* ctrl  = (unsigned*)alloc(256);                  // [0]=cand count, [1]=bin threshold
    unsigned* sup   = (unsigned*)alloc((size_t)6144 * 4);     // suppression flags
    unsigned* rank  = (unsigned*)alloc((size_t)CAP * 4);      // candidate ranks
    size_t zero_bytes = off;

    double* Xs64 = (double*)alloc((size_t)NB * HID * 8);
    double* Xo64 = (double*)alloc((size_t)NB * HID * 8);
    float*  XsT  = (float*)alloc((size_t)NB * HID * 4);
    float*  XoT  = (float*)alloc((size_t)NB * HID * 4);
    double* cval = (double*)alloc((size_t)CAP * 8);
    unsigned* cidx = (unsigned*)alloc((size_t)CAP * 4);
    double* svalv = (double*)alloc((size_t)TOPK * 8);
    unsigned* sidxv = (unsigned*)alloc((size_t)TOPK * 4);
    double* ub   = (double*)alloc((size_t)TOPK * 5 * 8);

    hipMemsetAsync(d_ws, 0, zero_bytes, stream);

    mlp_kernel<<<NB / 4, 256, 0, stream>>>(feat, W1s, b1s, W2s, b2s,
                                           W1o, b1o, W2o, b2o,
                                           Xs64, Xo64, XsT, XoT);
    scores_pass_a<<<dim3(8, 64), 256, 0, stream>>>(XsT, XoT, ghist);
    find_threshold<<<1, 256, 0, stream>>>(ghist, ctrl);
    scores_pass_b<<<dim3(64, 64), 256, 0, stream>>>(XsT, XoT, Xs64, Xo64, ctrl, cval, cidx);
    rank_count<<<dim3(CAP / 256, JSLICES), 256, 0, stream>>>(ctrl, cval, cidx, rank);
    rank_scatter<<<CAP / 256, 256, 0, stream>>>(ctrl, cval, cidx, rank, svalv, sidxv);
    nms_prep<<<(TOPK + 255) / 256, 256, 0, stream>>>(sidxv, rois, ub);
    nms_kernel<<<dim3((TOPK + 255) / 256, (TOPK + 255) / 256), 256, 0, stream>>>(ub, sup);
    finalize_kernel<<<1, 1024, 0, stream>>>(sup, svalv, sidxv, (float*)d_out);
}

// Round 5
// 453.748 us; speedup vs baseline: 2.4083x; 2.4083x over previous
//
#include <hip/hip_runtime.h>
#include <math.h>

// Problem constants
#define NB    8192          // N
#define FEAT  255
#define HID   64
#define TOPK  6000
#define POSTK 300
#define BINS  8192          // 13-bit sortable-float key bins (sign+8exp+4mant)
#define BSHIFT 19           // 32-13
#define CAP   131072        // candidate buffer capacity
#define CAPLIM 98304        // target upper bound on estimated candidate count
#define SLACK 1             // bins below bstar (f32 vs f64 noise; provably enough)
#define TSEL  1000          // sampled cnt_ge target (1/8 col sample => true >= 6000 at +9.7 sigma)
#define JSLICES 64          // j-dimension parallelism for rank counting

__device__ __forceinline__ unsigned binOf(float x) {
    unsigned u = __float_as_uint(x);
    u = (u & 0x80000000u) ? ~u : (u | 0x80000000u);   // sortable key (ascending)
    return u >> BSHIFT;
}

// ---------------------------------------------------------------------------
// K1: the two 255->64->64 MLPs in f64. One block = 4 rows, 64 threads/row.
// Writes row-major f64 (for candidate refine) and transposed f32 [k][n].
// ---------------------------------------------------------------------------
__global__ __launch_bounds__(256) void mlp_kernel(
    const float* __restrict__ feat,
    const float* __restrict__ W1s, const float* __restrict__ b1s,
    const float* __restrict__ W2s, const float* __restrict__ b2s,
    const float* __restrict__ W1o, const float* __restrict__ b1o,
    const float* __restrict__ W2o, const float* __restrict__ b2o,
    double* __restrict__ Xs64, double* __restrict__ Xo64,
    float* __restrict__ XsT, float* __restrict__ XoT)
{
    int tid  = threadIdx.x;
    int trow = tid >> 6;          // 0..3
    int t    = tid & 63;          // hidden unit
    int r    = blockIdx.x * 4 + trow;
    __shared__ double hs[4][64];
    __shared__ double ho[4][64];

    const float* frow = feat + (size_t)r * FEAT;
    double as = (double)b1s[t];
    double ao = (double)b1o[t];
    for (int k = 0; k < FEAT; ++k) {
        double fv = (double)frow[k];
        as += fv * (double)W1s[k * HID + t];
        ao += fv * (double)W1o[k * HID + t];
    }
    hs[trow][t] = as > 0.0 ? as : 0.0;
    ho[trow][t] = ao > 0.0 ? ao : 0.0;
    __syncthreads();

    double xs = (double)b2s[t];
    double xo = (double)b2o[t];
    for (int k = 0; k < HID; ++k) {
        xs += hs[trow][k] * (double)W2s[k * HID + t];
        xo += ho[trow][k] * (double)W2o[k * HID + t];
    }
    size_t o = (size_t)r * HID + t;
    Xs64[o] = xs;
    Xo64[o] = xo;
    XsT[(size_t)t * NB + r] = (float)xs;   // [k][n] layout for coalesced GEMM
    XoT[(size_t)t * NB + r] = (float)xo;
}

// ---------------------------------------------------------------------------
// K2: pass A — f32 logits for a 1/8 COLUMN SAMPLE (cols 0..1023).
// 128x128 tile / block, LDS-staged A/B tiles, 8x8 micro-tile per lane.
// Histogram of sortable keys in LDS, merged into global histogram.
// ---------------------------------------------------------------------------
__global__ __launch_bounds__(256) void scores_pass_a(
    const float* __restrict__ XsT, const float* __restrict__ XoT,
    unsigned* __restrict__ ghist)
{
    __shared__ float At[HID][128];    // 32 KB
    __shared__ float Bt[HID][128];    // 32 KB
    __shared__ unsigned hist[BINS];   // 32 KB
    int tid = threadIdx.x;
    for (int i = tid; i < BINS; i += 256) hist[i] = 0u;

    int r0base = blockIdx.y * 128;
    int c0base = blockIdx.x * 128;    // gridDim.x = 8 -> cols 0..1023
    for (int i = tid; i < HID * 32; i += 256) {
        int k = i >> 5, c4 = (i & 31) << 2;
        *(float4*)&At[k][c4] = *(const float4*)(XsT + (size_t)k * NB + r0base + c4);
        *(float4*)&Bt[k][c4] = *(const float4*)(XoT + (size_t)k * NB + c0base + c4);
    }
    __syncthreads();

    int tr = tid >> 4, tc = tid & 15;
    int r0 = r0base + tr * 8;
    int c0 = c0base + tc * 8;

    float acc[8][8];
#pragma unroll
    for (int i = 0; i < 8; ++i)
#pragma unroll
        for (int j = 0; j < 8; ++j) acc[i][j] = 0.0f;

#pragma unroll 2
    for (int k = 0; k < HID; ++k) {
        float a[8], b[8];
        *(float4*)&a[0] = *(float4*)&At[k][tr * 8];
        *(float4*)&a[4] = *(float4*)&At[k][tr * 8 + 4];
        *(float4*)&b[0] = *(float4*)&Bt[k][tc * 8];
        *(float4*)&b[4] = *(float4*)&Bt[k][tc * 8 + 4];
#pragma unroll
        for (int i = 0; i < 8; ++i)
#pragma unroll
            for (int j = 0; j < 8; ++j)
                acc[i][j] = fmaf(a[i], b[j], acc[i][j]);
    }

#pragma unroll
    for (int i = 0; i < 8; ++i)
#pragma unroll
        for (int j = 0; j < 8; ++j) {
            float v = acc[i][j];
            if (r0 + i == c0 + j) v = -1.0f;      // diagonal, like reference
            atomicAdd(&hist[binOf(v)], 1u);
        }

    __syncthreads();
    for (int i = tid; i < BINS; i += 256) {
        unsigned h = hist[i];
        if (h) atomicAdd(&ghist[i], h);
    }
}

// ---------------------------------------------------------------------------
// K3: from the SAMPLED histogram find bstar = largest bin with
// cnt_ge >= TSEL (=> true cnt_ge >= 6000 at +9.7 sigma), lower by SLACK,
// then walk up while the x8 extrapolated candidate count exceeds CAPLIM.
// ---------------------------------------------------------------------------
__global__ __launch_bounds__(256) void find_threshold(
    const unsigned* __restrict__ ghist, unsigned* __restrict__ ctrl)
{
    __shared__ unsigned csum[256];
    int tid  = threadIdx.x;
    int base = tid * (BINS / 256);
    unsigned s = 0;
    for (int i = 0; i < BINS / 256; ++i) s += ghist[base + i];
    csum[tid] = s;
    __syncthreads();
    if (tid == 0) {                       // suffix sums of chunk totals
        unsigned run = 0;
        for (int c = 255; c >= 0; --c) { run += csum[c]; csum[c] = run; }
    }
    __syncthreads();

    unsigned above = (tid == 255) ? 0u : csum[tid + 1];  // cnt_ge[chunk end]
    unsigned prev = above;
    for (int b = base + BINS / 256 - 1; b >= base; --b) {
        unsigned cur = prev + ghist[b];
        if (cur >= TSEL && prev < TSEL) {
            unsigned bstar = (unsigned)b;
            unsigned bt = bstar >= SLACK ? bstar - SLACK : 0;
            unsigned cnt = cur;
            for (unsigned bb = bstar; bb-- > bt;) cnt += ghist[bb];
            while (8u * cnt > CAPLIM && bt < bstar) { cnt -= ghist[bt]; bt++; }
            ctrl[1] = bt;
            break;
        }
        prev = cur;
    }
}

// ---------------------------------------------------------------------------
// K4: pass B — full f32 GEMM, LDS-staged tiles. Elements whose f32 bin
// clears the threshold are ballot-compacted (index only, one atomic per
// wave). No f64 work here — refine_kernel does it with full parallelism.
// ---------------------------------------------------------------------------
__global__ __launch_bounds__(256) void scores_pass_b(
    const float* __restrict__ XsT, const float* __restrict__ XoT,
    unsigned* __restrict__ ctrl, unsigned* __restrict__ cidx)
{
    __shared__ float At[HID][128];    // 32 KB
    __shared__ float Bt[HID][128];    // 32 KB
    int tid = threadIdx.x;
    unsigned bt = ctrl[1];

    int r0base = blockIdx.y * 128;
    int c0base = blockIdx.x * 128;
    for (int i = tid; i < HID * 32; i += 256) {
        int k = i >> 5, c4 = (i & 31) << 2;
        *(float4*)&At[k][c4] = *(const float4*)(XsT + (size_t)k * NB + r0base + c4);
        *(float4*)&Bt[k][c4] = *(const float4*)(XoT + (size_t)k * NB + c0base + c4);
    }
    __syncthreads();

    int tr = tid >> 4, tc = tid & 15;
    int r0 = r0base + tr * 8;
    int c0 = c0base + tc * 8;
    int lane = tid & 63;

    float acc[8][8];
#pragma unroll
    for (int i = 0; i < 8; ++i)
#pragma unroll
        for (int j = 0; j < 8; ++j) acc[i][j] = 0.0f;

#pragma unroll 2
    for (int k = 0; k < HID; ++k) {
        float a[8], b[8];
        *(float4*)&a[0] = *(float4*)&At[k][tr * 8];
        *(float4*)&a[4] = *(float4*)&At[k][tr * 8 + 4];
        *(float4*)&b[0] = *(float4*)&Bt[k][tc * 8];
        *(float4*)&b[4] = *(float4*)&Bt[k][tc * 8 + 4];
#pragma unroll
        for (int i = 0; i < 8; ++i)
#pragma unroll
            for (int j = 0; j < 8; ++j)
                acc[i][j] = fmaf(a[i], b[j], acc[i][j]);
    }

#pragma unroll
    for (int i = 0; i < 8; ++i)
#pragma unroll
        for (int j = 0; j < 8; ++j) {
            int r = r0 + i, c = c0 + j;
            float v = acc[i][j];
            if (r == c) v = -1.0f;
            bool pred = binOf(v) >= bt;
            unsigned long long m = __ballot(pred);
            if (m) {
                unsigned nb = (unsigned)__popcll(m);
                int leader = __ffsll((long long)m) - 1;
                unsigned base = 0;
                if (lane == leader) base = atomicAdd(&ctrl[0], nb);
                base = __shfl(base, leader);
                if (pred) {
                    unsigned off = (unsigned)__popcll(m & ((1ull << lane) - 1ull));
                    unsigned p = base + off;
                    if (p < CAP)
                        cidx[p] = (unsigned)r * (unsigned)NB + (unsigned)c;
                }
            }
        }
}

// ---------------------------------------------------------------------------
// K4b: refine — one wave per candidate: 64 coalesced f64 loads, product,
// butterfly reduce (deterministic order; f64 noise 1e-15 << 1e-5 rank gaps).
// ---------------------------------------------------------------------------
__global__ __launch_bounds__(256) void refine_kernel(
    const unsigned* __restrict__ ctrl, const unsigned* __restrict__ cidx,
    const double* __restrict__ Xs64, const double* __restrict__ Xo64,
    double* __restrict__ cval)
{
    unsigned M = ctrl[0];
    if (M > CAP) M = CAP;
    unsigned w = blockIdx.x * 4u + (threadIdx.x >> 6);
    if (w >= M) return;
    int lane = threadIdx.x & 63;
    unsigned id = cidx[w];
    unsigned r = id >> 13, c = id & (NB - 1);
    double p = Xs64[(size_t)r * HID + lane] * Xo64[(size_t)c * HID + lane];
#pragma unroll
    for (int s = 32; s > 0; s >>= 1) p += __shfl_xor(p, s);
    if (lane == 0) cval[w] = (r == c) ? -1.0 : p;
}

// ---------------------------------------------------------------------------
// K5a: rank-by-counting, 2-D parallel. Grid (i_tile, j_slice). Each block
// counts its 256 candidates against one j-slice (LDS-staged 256 at a time)
// and atomically accumulates into rank[]. Composite key: value desc, flat
// index asc (jax top_k tie-break).
// ---------------------------------------------------------------------------
__global__ __launch_bounds__(256) void rank_count(
    const unsigned* __restrict__ ctrl,
    const double* __restrict__ cval, const unsigned* __restrict__ cidx,
    unsigned* __restrict__ rank)
{
    unsigned M = ctrl[0];
    if (M > CAP) M = CAP;
    unsigned itile = blockIdx.x;
    if (itile * 256u >= M) return;

    unsigned t = itile * 256u + threadIdx.x;
    bool act = t < M;
    double v  = act ? cval[t] : 0.0;
    unsigned id = act ? cidx[t] : 0u;
    unsigned cnt = 0;

    unsigned slice = blockIdx.y;
    unsigned jbeg = (unsigned)(((unsigned long long)slice * M) / JSLICES);
    unsigned jend = (unsigned)(((unsigned long long)(slice + 1) * M) / JSLICES);

    __shared__ double  lv[256];
    __shared__ unsigned li[256];
    for (unsigned base = jbeg; base < jend; base += 256u) {
        unsigned j = base + threadIdx.x;
        if (j < jend) { lv[threadIdx.x] = cval[j]; li[threadIdx.x] = cidx[j]; }
        __syncthreads();
        unsigned lim = jend - base; if (lim > 256u) lim = 256u;
        if (act) {
            for (unsigned e = 0; e < lim; ++e) {
                double ev = lv[e];
                cnt += (ev > v) || (ev == v && li[e] < id);
            }
        }
        __syncthreads();
    }
    if (act && cnt) atomicAdd(&rank[t], cnt);
}

// ---------------------------------------------------------------------------
// K5b: scatter candidates with rank < TOPK into sorted arrays.
// ---------------------------------------------------------------------------
__global__ __launch_bounds__(256) void rank_scatter(
    const unsigned* __restrict__ ctrl,
    const double* __restrict__ cval, const unsigned* __restrict__ cidx,
    const unsigned* __restrict__ rank,
    double* __restrict__ sval, unsigned* __restrict__ sidx)
{
    unsigned M = ctrl[0];
    if (M > CAP) M = CAP;
    unsigned t = blockIdx.x * 256u + threadIdx.x;
    if (t >= M) return;
    unsigned r = rank[t];
    if (r < TOPK) { sval[r] = cval[t]; sidx[r] = cidx[t]; }
}

// ---------------------------------------------------------------------------
// K6: union boxes + 0.7*area for the sorted TOPK pairs.
// ---------------------------------------------------------------------------
__global__ __launch_bounds__(256) void nms_prep(
    const unsigned* __restrict__ sidx, const float* __restrict__ rois,
    double* __restrict__ ub)
{
    int t = blockIdx.x * 256 + threadIdx.x;
    if (t >= TOPK) return;
    unsigned id = sidx[t];
    unsigned s = id >> 13, o = id & (NB - 1);
    const float* bs = rois + (size_t)s * 5;
    const float* bo = rois + (size_t)o * 5;
    double x1 = fmin((double)bs[1], (double)bo[1]);
    double y1 = fmin((double)bs[2], (double)bo[2]);
    double x2 = fmax((double)bs[3], (double)bo[3]);
    double y2 = fmax((double)bs[4], (double)bo[4]);
    double area = (x2 - x1) * (y2 - y1);
    double* u = ub + (size_t)t * 5;
    u[0] = x1; u[1] = y1; u[2] = x2; u[3] = y2; u[4] = 0.7 * area;
}

// ---------------------------------------------------------------------------
// K7: suppressed[j] = OR_{i<j} (iou > 0.7). Division-free equivalent:
// inter/(ai+aj-inter+1e-8) > 0.7  <=>  1.7*inter > 0.7*ai + 0.7*aj + 7e-9.
// ---------------------------------------------------------------------------
__global__ __launch_bounds__(256) void nms_kernel(
    const double* __restrict__ ub, unsigned* __restrict__ sup)
{
    int jb = blockIdx.x, ib = blockIdx.y;
    if (ib > jb) return;
    __shared__ double L[256][5];
    int tid = threadIdx.x;
    int ibase = ib * 256;
    int icount = TOPK - ibase; if (icount > 256) icount = 256;
    if (tid < icount) {
        const double* u = ub + (size_t)(ibase + tid) * 5;
#pragma unroll
        for (int q = 0; q < 5; ++q) L[tid][q] = u[q];
    }
    __syncthreads();

    int j = jb * 256 + tid;
    if (j >= TOPK) return;
    const double* u = ub + (size_t)j * 5;
    double x1 = u[0], y1 = u[1], x2 = u[2], y2 = u[3], pa = u[4];
    int lim = j - ibase; if (lim > icount) lim = icount;  // i < j
    bool flag = false;
    for (int e = 0; e < lim; ++e) {
        double ix1 = fmax(L[e][0], x1);
        double iy1 = fmax(L[e][1], y1);
        double ix2 = fmin(L[e][2], x2);
        double iy2 = fmin(L[e][3], y2);
        double iw = ix2 - ix1; iw = iw > 0.0 ? iw : 0.0;
        double ih = iy2 - iy1; ih = ih > 0.0 ? ih : 0.0;
        double inter = iw * ih;
        if (1.7 * inter > pa + L[e][4] + 7e-9) { flag = true; break; }
    }
    if (flag) atomicOr(&sup[j], 1u);
}

// ---------------------------------------------------------------------------
// K8: top-300 of where(sup,-1,score) over the descending-sorted list is a
// stable partition (unsuppressed first, then suppressed with score -1).
// Single block, chunked LDS scan. Writes all 900 output floats.
// ---------------------------------------------------------------------------
__global__ __launch_bounds__(1024) void finalize_kernel(
    const unsigned* __restrict__ sup, const double* __restrict__ sval,
    const unsigned* __restrict__ sidx, float* __restrict__ out)
{
    __shared__ unsigned pref[1024];
    __shared__ unsigned bases[2];   // running {unsup, sup} counts
    __shared__ unsigned totalu;
    int tid = threadIdx.x;

    unsigned s = 0;
    for (int i = tid; i < TOPK; i += 1024) s += (sup[i] == 0u);
    pref[tid] = s;
    __syncthreads();
    for (int st = 512; st > 0; st >>= 1) {
        if (tid < st) pref[tid] += pref[tid + st];
        __syncthreads();
    }
    if (tid == 0) { totalu = pref[0]; bases[0] = 0; bases[1] = 0; }
    __syncthreads();

    for (int c = 0; c < (TOPK + 1023) / 1024; ++c) {
        int idx = c * 1024 + tid;
        int valid = TOPK - c * 1024; if (valid > 1024) valid = 1024;
        unsigned f = (idx < TOPK && sup[idx] == 0u) ? 1u : 0u;
        pref[tid] = f;
        __syncthreads();
        for (int st = 1; st < 1024; st <<= 1) {
            unsigned add = (tid >= st) ? pref[tid - st] : 0u;
            __syncthreads();
            pref[tid] += add;
            __syncthreads();
        }
        if (idx < TOPK) {
            unsigned incl = pref[tid];
            unsigned e = incl - f;                     // unsup before me in chunk
            unsigned pos = f ? (bases[0] + e)
                             : (totalu + bases[1] + (unsigned)tid - e);
            if (pos < POSTK) {
                unsigned id = sidx[idx];
                unsigned sb = id >> 13, ob = id & (NB - 1);
                out[2 * pos]     = (float)sb;
                out[2 * pos + 1] = (float)ob;
                double sg = f ? 1.0 / (1.0 + exp(-sval[idx])) : -1.0;
                out[2 * POSTK + pos] = (float)sg;
            }
        }
        __syncthreads();
        if (tid == 0) {
            unsigned inclLast = pref[valid - 1];
            bases[0] += inclLast;
            bases[1] += (unsigned)valid - inclLast;
        }
        __syncthreads();
    }
}

// ---------------------------------------------------------------------------
extern "C" void kernel_launch(void* const* d_in, const int* in_sizes, int n_in,
                              void* d_out, int out_size, void* d_ws, size_t ws_size,
                              hipStream_t stream)
{
    const float* rois = (const float*)d_in[0];
    const float* feat = (const float*)d_in[1];
    const float* W1s  = (const float*)d_in[2];
    const float* b1s  = (const float*)d_in[3];
    const float* W2s  = (const float*)d_in[4];
    const float* b2s  = (const float*)d_in[5];
    const float* W1o  = (const float*)d_in[6];
    const float* b1o  = (const float*)d_in[7];
    const float* W2o  = (const float*)d_in[8];
    const float* b2o  = (const float*)d_in[9];

    char* ws = (char*)d_ws;
    size_t off = 0;
    auto alloc = [&](size_t bytes) -> void* {
        off = (off + 255) & ~(size_t)255;
        void* p = ws + off;
        off += bytes;
        return p;
    };

    // zeroed region first
    unsigned* ghist = (unsigned*)alloc((size_t)BINS * 4);     // histogram
    unsigned* ctrl  = (unsigned*)alloc(256);                  // [0]=cand count, [1]=bin threshold
    unsigned* sup   = (unsigned*)alloc((size_t)6144 * 4);     // suppression flags
    unsigned* rank  = (unsigned*)alloc((size_t)CAP * 4);      // candidate ranks
    size_t zero_bytes = off;

    double* Xs64 = (double*)alloc((size_t)NB * HID * 8);
    double* Xo64 = (double*)alloc((size_t)NB * HID * 8);
    float*  XsT  = (float*)alloc((size_t)NB * HID * 4);
    float*  XoT  = (float*)alloc((size_t)NB * HID * 4);
    double* cval = (double*)alloc((size_t)CAP * 8);
    unsigned* cidx = (unsigned*)alloc((size_t)CAP * 4);
    double* svalv = (double*)alloc((size_t)TOPK * 8);
    unsigned* sidxv = (unsigned*)alloc((size_t)TOPK * 4);
    double* ub   = (double*)alloc((size_t)TOPK * 5 * 8);

    hipMemsetAsync(d_ws, 0, zero_bytes, stream);

    mlp_kernel<<<NB / 4, 256, 0, stream>>>(feat, W1s, b1s, W2s, b2s,
                                           W1o, b1o, W2o, b2o,
                                           Xs64, Xo64, XsT, XoT);
    scores_pass_a<<<dim3(8, 64), 256, 0, stream>>>(XsT, XoT, ghist);
    find_threshold<<<1, 256, 0, stream>>>(ghist, ctrl);
    scores_pass_b<<<dim3(64, 64), 256, 0, stream>>>(XsT, XoT, ctrl, cidx);
    refine_kernel<<<CAP / 4, 256, 0, stream>>>(ctrl, cidx, Xs64, Xo64, cval);
    rank_count<<<dim3(CAP / 256, JSLICES), 256, 0, stream>>>(ctrl, cval, cidx, rank);
    rank_scatter<<<CAP / 256, 256, 0, stream>>>(ctrl, cval, cidx, rank, svalv, sidxv);
    nms_prep<<<(TOPK + 255) / 256, 256, 0, stream>>>(sidxv, rois, ub);
    nms_kernel<<<dim3((TOPK + 255) / 256, (TOPK + 255) / 256), 256, 0, stream>>>(ub, sup);
    finalize_kernel<<<1, 1024, 0, stream>>>(sup, svalv, sidxv, (float*)d_out);
}

// Round 6
// 410.872 us; speedup vs baseline: 2.6596x; 1.1044x over previous
//
#include <hip/hip_runtime.h>
#include <math.h>

// Problem constants
#define NB    8192          // N
#define FEAT  255
#define HID   64
#define TOPK  6000
#define POSTK 300
#define BINS  8192          // 13-bit sortable-float key bins (sign+8exp+4mant)
#define BSHIFT 19           // 32-13
#define CAP   131072        // candidate buffer capacity
#define CAPLIM 98304        // target upper bound on estimated candidate count
#define SLACK 1             // bins below bstar (bf16-mfma vs f64 err 0.03 << bin 0.5)
#define TSEL  1000          // sampled cnt_ge target (1/8 col sample => true >= 6000 at +9.7 sigma)
#define JSLICES 64          // j-dimension parallelism for rank counting

typedef __attribute__((ext_vector_type(8))) short bf16x8;
typedef __attribute__((ext_vector_type(4))) float f32x4;

__device__ __forceinline__ unsigned binOf(float x) {
    unsigned u = __float_as_uint(x);
    u = (u & 0x80000000u) ? ~u : (u | 0x80000000u);   // sortable key (ascending)
    return u >> BSHIFT;
}

__device__ __forceinline__ unsigned short f2bf(float f) {   // RNE bf16 (finite inputs)
    unsigned u = __float_as_uint(f);
    return (unsigned short)((u + 0x7fffu + ((u >> 16) & 1u)) >> 16);
}

// ---------------------------------------------------------------------------
// K1: the two 255->64->64 MLPs in f64. One block = 4 rows, 64 threads/row.
// Writes row-major f64 (refine path) and row-major bf16 [n][64] (MFMA path).
// ---------------------------------------------------------------------------
__global__ __launch_bounds__(256) void mlp_kernel(
    const float* __restrict__ feat,
    const float* __restrict__ W1s, const float* __restrict__ b1s,
    const float* __restrict__ W2s, const float* __restrict__ b2s,
    const float* __restrict__ W1o, const float* __restrict__ b1o,
    const float* __restrict__ W2o, const float* __restrict__ b2o,
    double* __restrict__ Xs64, double* __restrict__ Xo64,
    unsigned short* __restrict__ Xsb, unsigned short* __restrict__ Xob)
{
    int tid  = threadIdx.x;
    int trow = tid >> 6;          // 0..3
    int t    = tid & 63;          // hidden unit
    int r    = blockIdx.x * 4 + trow;
    __shared__ double hs[4][64];
    __shared__ double ho[4][64];

    const float* frow = feat + (size_t)r * FEAT;
    double as = (double)b1s[t];
    double ao = (double)b1o[t];
    for (int k = 0; k < FEAT; ++k) {
        double fv = (double)frow[k];
        as += fv * (double)W1s[k * HID + t];
        ao += fv * (double)W1o[k * HID + t];
    }
    hs[trow][t] = as > 0.0 ? as : 0.0;
    ho[trow][t] = ao > 0.0 ? ao : 0.0;
    __syncthreads();

    double xs = (double)b2s[t];
    double xo = (double)b2o[t];
    for (int k = 0; k < HID; ++k) {
        xs += hs[trow][k] * (double)W2s[k * HID + t];
        xo += ho[trow][k] * (double)W2o[k * HID + t];
    }
    size_t o = (size_t)r * HID + t;
    Xs64[o] = xs;
    Xo64[o] = xo;
    Xsb[o] = f2bf((float)xs);
    Xob[o] = f2bf((float)xo);
}

// ---------------------------------------------------------------------------
// MFMA core: one block = 128x128 tile, 4 waves in 2x2, each wave 64x64 via
// 4x4 grid of 16x16x32 bf16 MFMAs over K=64 (2 k-chunks). Fragments load
// 16B of contiguous k directly from row-major bf16 [n][64] arrays.
// C/D layout (m89-verified): col=lane&15, row=quad*4+reg.
// ---------------------------------------------------------------------------
#define MFMA_COMPUTE(ACC)                                                     \
    f32x4 ACC[4][4];                                                          \
    _Pragma("unroll")                                                         \
    for (int ti = 0; ti < 4; ++ti)                                            \
        _Pragma("unroll")                                                     \
        for (int tj = 0; tj < 4; ++tj) ACC[ti][tj] = (f32x4){0,0,0,0};        \
    _Pragma("unroll")                                                         \
    for (int kc = 0; kc < 2; ++kc) {                                          \
        bf16x8 afr[4], bfr[4];                                                \
        _Pragma("unroll")                                                     \
        for (int t = 0; t < 4; ++t) {                                         \
            afr[t] = *(const bf16x8*)(Xsb + (size_t)(r0 + t * 16 + l16) * HID \
                                      + kc * 32 + quad * 8);                  \
            bfr[t] = *(const bf16x8*)(Xob + (size_t)(c0 + t * 16 + l16) * HID \
                                      + kc * 32 + quad * 8);                  \
        }                                                                     \
        _Pragma("unroll")                                                     \
        for (int ti = 0; ti < 4; ++ti)                                        \
            _Pragma("unroll")                                                 \
            for (int tj = 0; tj < 4; ++tj)                                    \
                ACC[ti][tj] = __builtin_amdgcn_mfma_f32_16x16x32_bf16(        \
                    afr[ti], bfr[tj], ACC[ti][tj], 0, 0, 0);                  \
    }

// ---------------------------------------------------------------------------
// K2: histogram pass over the 1/8 column sample (cols 0..1023).
// ---------------------------------------------------------------------------
__global__ __launch_bounds__(256) void mfma_hist(
    const unsigned short* __restrict__ Xsb, const unsigned short* __restrict__ Xob,
    unsigned* __restrict__ ghist)
{
    __shared__ unsigned hist[BINS];   // 32 KB
    int tid = threadIdx.x;
    for (int i = tid; i < BINS; i += 256) hist[i] = 0u;
    __syncthreads();

    int lane = tid & 63;
    int wave = tid >> 6;
    int quad = lane >> 4;
    int l16  = lane & 15;
    int r0 = blockIdx.y * 128 + (wave >> 1) * 64;
    int c0 = blockIdx.x * 128 + (wave & 1) * 64;   // gridDim.x = 8 -> cols 0..1023

    MFMA_COMPUTE(acc)

#pragma unroll
    for (int ti = 0; ti < 4; ++ti)
#pragma unroll
        for (int tj = 0; tj < 4; ++tj)
#pragma unroll
            for (int i = 0; i < 4; ++i) {
                int r = r0 + ti * 16 + quad * 4 + i;
                int c = c0 + tj * 16 + l16;
                float v = acc[ti][tj][i];
                if (r == c) v = -1.0f;
                atomicAdd(&hist[binOf(v)], 1u);
            }

    __syncthreads();
    for (int i = tid; i < BINS; i += 256) {
        unsigned h = hist[i];
        if (h) atomicAdd(&ghist[i], h);
    }
}

// ---------------------------------------------------------------------------
// K3: from the SAMPLED histogram find bstar = largest bin with
// cnt_ge >= TSEL, lower by SLACK, walk up while x8 estimate exceeds CAPLIM.
// ---------------------------------------------------------------------------
__global__ __launch_bounds__(256) void find_threshold(
    const unsigned* __restrict__ ghist, unsigned* __restrict__ ctrl)
{
    __shared__ unsigned csum[256];
    int tid  = threadIdx.x;
    int base = tid * (BINS / 256);
    unsigned s = 0;
    for (int i = 0; i < BINS / 256; ++i) s += ghist[base + i];
    csum[tid] = s;
    __syncthreads();
    if (tid == 0) {                       // suffix sums of chunk totals
        unsigned run = 0;
        for (int c = 255; c >= 0; --c) { run += csum[c]; csum[c] = run; }
    }
    __syncthreads();

    unsigned above = (tid == 255) ? 0u : csum[tid + 1];  // cnt_ge[chunk end]
    unsigned prev = above;
    for (int b = base + BINS / 256 - 1; b >= base; --b) {
        unsigned cur = prev + ghist[b];
        if (cur >= TSEL && prev < TSEL) {
            unsigned bstar = (unsigned)b;
            unsigned bt = bstar >= SLACK ? bstar - SLACK : 0;
            unsigned cnt = cur;
            for (unsigned bb = bstar; bb-- > bt;) cnt += ghist[bb];
            while (8u * cnt > CAPLIM && bt < bstar) { cnt -= ghist[bt]; bt++; }
            ctrl[1] = bt;
            break;
        }
        prev = cur;
    }
}

// ---------------------------------------------------------------------------
// K4: filter pass over the full matrix; elements whose bf16-MFMA bin clears
// the threshold are ballot-compacted (index only, one atomic per wave).
// ---------------------------------------------------------------------------
__global__ __launch_bounds__(256) void mfma_filter(
    const unsigned short* __restrict__ Xsb, const unsigned short* __restrict__ Xob,
    unsigned* __restrict__ ctrl, unsigned* __restrict__ cidx)
{
    unsigned bt = ctrl[1];
    int tid = threadIdx.x;
    int lane = tid & 63;
    int wave = tid >> 6;
    int quad = lane >> 4;
    int l16  = lane & 15;
    int r0 = blockIdx.y * 128 + (wave >> 1) * 64;
    int c0 = blockIdx.x * 128 + (wave & 1) * 64;

    MFMA_COMPUTE(acc)

#pragma unroll
    for (int ti = 0; ti < 4; ++ti)
#pragma unroll
        for (int tj = 0; tj < 4; ++tj)
#pragma unroll
            for (int i = 0; i < 4; ++i) {
                int r = r0 + ti * 16 + quad * 4 + i;
                int c = c0 + tj * 16 + l16;
                float v = acc[ti][tj][i];
                if (r == c) v = -1.0f;
                bool pred = binOf(v) >= bt;
                unsigned long long m = __ballot(pred);
                if (m) {
                    unsigned nb = (unsigned)__popcll(m);
                    int leader = __ffsll((long long)m) - 1;
                    unsigned base = 0;
                    if (lane == leader) base = atomicAdd(&ctrl[0], nb);
                    base = __shfl(base, leader);
                    if (pred) {
                        unsigned off = (unsigned)__popcll(m & ((1ull << lane) - 1ull));
                        unsigned p = base + off;
                        if (p < CAP)
                            cidx[p] = (unsigned)r * (unsigned)NB + (unsigned)c;
                    }
                }
            }
}

// ---------------------------------------------------------------------------
// K4b: refine — one wave per candidate: 64 coalesced f64 loads, product,
// butterfly reduce (deterministic order; f64 noise 1e-15 << 1e-5 rank gaps).
// ---------------------------------------------------------------------------
__global__ __launch_bounds__(256) void refine_kernel(
    const unsigned* __restrict__ ctrl, const unsigned* __restrict__ cidx,
    const double* __restrict__ Xs64, const double* __restrict__ Xo64,
    double* __restrict__ cval)
{
    unsigned M = ctrl[0];
    if (M > CAP) M = CAP;
    unsigned w = blockIdx.x * 4u + (threadIdx.x >> 6);
    if (w >= M) return;
    int lane = threadIdx.x & 63;
    unsigned id = cidx[w];
    unsigned r = id >> 13, c = id & (NB - 1);
    double p = Xs64[(size_t)r * HID + lane] * Xo64[(size_t)c * HID + lane];
#pragma unroll
    for (int s = 32; s > 0; s >>= 1) p += __shfl_xor(p, s);
    if (lane == 0) cval[w] = (r == c) ? -1.0 : p;
}

// ---------------------------------------------------------------------------
// K5a: rank-by-counting, 2-D parallel. Composite key: value desc, flat
// index asc (jax top_k tie-break).
// ---------------------------------------------------------------------------
__global__ __launch_bounds__(256) void rank_count(
    const unsigned* __restrict__ ctrl,
    const double* __restrict__ cval, const unsigned* __restrict__ cidx,
    unsigned* __restrict__ rank)
{
    unsigned M = ctrl[0];
    if (M > CAP) M = CAP;
    unsigned itile = blockIdx.x;
    if (itile * 256u >= M) return;

    unsigned t = itile * 256u + threadIdx.x;
    bool act = t < M;
    double v  = act ? cval[t] : 0.0;
    unsigned id = act ? cidx[t] : 0u;
    unsigned cnt = 0;

    unsigned slice = blockIdx.y;
    unsigned jbeg = (unsigned)(((unsigned long long)slice * M) / JSLICES);
    unsigned jend = (unsigned)(((unsigned long long)(slice + 1) * M) / JSLICES);

    __shared__ double  lv[256];
    __shared__ unsigned li[256];
    for (unsigned base = jbeg; base < jend; base += 256u) {
        unsigned j = base + threadIdx.x;
        if (j < jend) { lv[threadIdx.x] = cval[j]; li[threadIdx.x] = cidx[j]; }
        __syncthreads();
        unsigned lim = jend - base; if (lim > 256u) lim = 256u;
        if (act) {
            for (unsigned e = 0; e < lim; ++e) {
                double ev = lv[e];
                cnt += (ev > v) || (ev == v && li[e] < id);
            }
        }
        __syncthreads();
    }
    if (act && cnt) atomicAdd(&rank[t], cnt);
}

// ---------------------------------------------------------------------------
// K5b: scatter candidates with rank < TOPK into sorted arrays.
// ---------------------------------------------------------------------------
__global__ __launch_bounds__(256) void rank_scatter(
    const unsigned* __restrict__ ctrl,
    const double* __restrict__ cval, const unsigned* __restrict__ cidx,
    const unsigned* __restrict__ rank,
    double* __restrict__ sval, unsigned* __restrict__ sidx)
{
    unsigned M = ctrl[0];
    if (M > CAP) M = CAP;
    unsigned t = blockIdx.x * 256u + threadIdx.x;
    if (t >= M) return;
    unsigned r = rank[t];
    if (r < TOPK) { sval[r] = cval[t]; sidx[r] = cidx[t]; }
}

// ---------------------------------------------------------------------------
// K6: union boxes + 0.7*area for the sorted TOPK pairs.
// ---------------------------------------------------------------------------
__global__ __launch_bounds__(256) void nms_prep(
    const unsigned* __restrict__ sidx, const float* __restrict__ rois,
    double* __restrict__ ub)
{
    int t = blockIdx.x * 256 + threadIdx.x;
    if (t >= TOPK) return;
    unsigned id = sidx[t];
    unsigned s = id >> 13, o = id & (NB - 1);
    const float* bs = rois + (size_t)s * 5;
    const float* bo = rois + (size_t)o * 5;
    double x1 = fmin((double)bs[1], (double)bo[1]);
    double y1 = fmin((double)bs[2], (double)bo[2]);
    double x2 = fmax((double)bs[3], (double)bo[3]);
    double y2 = fmax((double)bs[4], (double)bo[4]);
    double area = (x2 - x1) * (y2 - y1);
    double* u = ub + (size_t)t * 5;
    u[0] = x1; u[1] = y1; u[2] = x2; u[3] = y2; u[4] = 0.7 * area;
}

// ---------------------------------------------------------------------------
// K7: suppressed[j] = OR_{i<j} (iou > 0.7). Division-free equivalent:
// inter/(ai+aj-inter+1e-8) > 0.7  <=>  1.7*inter > 0.7*ai + 0.7*aj + 7e-9.
// ---------------------------------------------------------------------------
__global__ __launch_bounds__(256) void nms_kernel(
    const double* __restrict__ ub, unsigned* __restrict__ sup)
{
    int jb = blockIdx.x, ib = blockIdx.y;
    if (ib > jb) return;
    __shared__ double L[256][5];
    int tid = threadIdx.x;
    int ibase = ib * 256;
    int icount = TOPK - ibase; if (icount > 256) icount = 256;
    if (tid < icount) {
        const double* u = ub + (size_t)(ibase + tid) * 5;
#pragma unroll
        for (int q = 0; q < 5; ++q) L[tid][q] = u[q];
    }
    __syncthreads();

    int j = jb * 256 + tid;
    if (j >= TOPK) return;
    const double* u = ub + (size_t)j * 5;
    double x1 = u[0], y1 = u[1], x2 = u[2], y2 = u[3], pa = u[4];
    int lim = j - ibase; if (lim > icount) lim = icount;  // i < j
    bool flag = false;
    for (int e = 0; e < lim; ++e) {
        double ix1 = fmax(L[e][0], x1);
        double iy1 = fmax(L[e][1], y1);
        double ix2 = fmin(L[e][2], x2);
        double iy2 = fmin(L[e][3], y2);
        double iw = ix2 - ix1; iw = iw > 0.0 ? iw : 0.0;
        double ih = iy2 - iy1; ih = ih > 0.0 ? ih : 0.0;
        double inter = iw * ih;
        if (1.7 * inter > pa + L[e][4] + 7e-9) { flag = true; break; }
    }
    if (flag) atomicOr(&sup[j], 1u);
}

// ---------------------------------------------------------------------------
// K8: top-300 of where(sup,-1,score) over the descending-sorted list is a
// stable partition (unsuppressed first, then suppressed with score -1).
// Single block, chunked LDS scan. Writes all 900 output floats.
// ---------------------------------------------------------------------------
__global__ __launch_bounds__(1024) void finalize_kernel(
    const unsigned* __restrict__ sup, const double* __restrict__ sval,
    const unsigned* __restrict__ sidx, float* __restrict__ out)
{
    __shared__ unsigned pref[1024];
    __shared__ unsigned bases[2];   // running {unsup, sup} counts
    __shared__ unsigned totalu;
    int tid = threadIdx.x;

    unsigned s = 0;
    for (int i = tid; i < TOPK; i += 1024) s += (sup[i] == 0u);
    pref[tid] = s;
    __syncthreads();
    for (int st = 512; st > 0; st >>= 1) {
        if (tid < st) pref[tid] += pref[tid + st];
        __syncthreads();
    }
    if (tid == 0) { totalu = pref[0]; bases[0] = 0; bases[1] = 0; }
    __syncthreads();

    for (int c = 0; c < (TOPK + 1023) / 1024; ++c) {
        int idx = c * 1024 + tid;
        int valid = TOPK - c * 1024; if (valid > 1024) valid = 1024;
        unsigned f = (idx < TOPK && sup[idx] == 0u) ? 1u : 0u;
        pref[tid] = f;
        __syncthreads();
        for (int st = 1; st < 1024; st <<= 1) {
            unsigned add = (tid >= st) ? pref[tid - st] : 0u;
            __syncthreads();
            pref[tid] += add;
            __syncthreads();
        }
        if (idx < TOPK) {
            unsigned incl = pref[tid];
            unsigned e = incl - f;                     // unsup before me in chunk
            unsigned pos = f ? (bases[0] + e)
                             : (totalu + bases[1] + (unsigned)tid - e);
            if (pos < POSTK) {
                unsigned id = sidx[idx];
                unsigned sb = id >> 13, ob = id & (NB - 1);
                out[2 * pos]     = (float)sb;
                out[2 * pos + 1] = (float)ob;
                double sg = f ? 1.0 / (1.0 + exp(-sval[idx])) : -1.0;
                out[2 * POSTK + pos] = (float)sg;
            }
        }
        __syncthreads();
        if (tid == 0) {
            unsigned inclLast = pref[valid - 1];
            bases[0] += inclLast;
            bases[1] += (unsigned)valid - inclLast;
        }
        __syncthreads();
    }
}

// ---------------------------------------------------------------------------
extern "C" void kernel_launch(void* const* d_in, const int* in_sizes, int n_in,
                              void* d_out, int out_size, void* d_ws, size_t ws_size,
                              hipStream_t stream)
{
    const float* rois = (const float*)d_in[0];
    const float* feat = (const float*)d_in[1];
    const float* W1s  = (const float*)d_in[2];
    const float* b1s  = (const float*)d_in[3];
    const float* W2s  = (const float*)d_in[4];
    const float* b2s  = (const float*)d_in[5];
    const float* W1o  = (const float*)d_in[6];
    const float* b1o  = (const float*)d_in[7];
    const float* W2o  = (const float*)d_in[8];
    const float* b2o  = (const float*)d_in[9];

    char* ws = (char*)d_ws;
    size_t off = 0;
    auto alloc = [&](size_t bytes) -> void* {
        off = (off + 255) & ~(size_t)255;
        void* p = ws + off;
        off += bytes;
        return p;
    };

    // zeroed region first
    unsigned* ghist = (unsigned*)alloc((size_t)BINS * 4);     // histogram
    unsigned* ctrl  = (unsigned*)alloc(256);                  // [0]=cand count, [1]=bin threshold
    unsigned* sup   = (unsigned*)alloc((size_t)6144 * 4);     // suppression flags
    unsigned* rank  = (unsigned*)alloc((size_t)CAP * 4);      // candidate ranks
    size_t zero_bytes = off;

    double* Xs64 = (double*)alloc((size_t)NB * HID * 8);
    double* Xo64 = (double*)alloc((size_t)NB * HID * 8);
    unsigned short* Xsb = (unsigned short*)alloc((size_t)NB * HID * 2);
    unsigned short* Xob = (unsigned short*)alloc((size_t)NB * HID * 2);
    double* cval = (double*)alloc((size_t)CAP * 8);
    unsigned* cidx = (unsigned*)alloc((size_t)CAP * 4);
    double* svalv = (double*)alloc((size_t)TOPK * 8);
    unsigned* sidxv = (unsigned*)alloc((size_t)TOPK * 4);
    double* ub   = (double*)alloc((size_t)TOPK * 5 * 8);

    hipMemsetAsync(d_ws, 0, zero_bytes, stream);

    mlp_kernel<<<NB / 4, 256, 0, stream>>>(feat, W1s, b1s, W2s, b2s,
                                           W1o, b1o, W2o, b2o,
                                           Xs64, Xo64, Xsb, Xob);
    mfma_hist<<<dim3(8, 64), 256, 0, stream>>>(Xsb, Xob, ghist);
    find_threshold<<<1, 256, 0, stream>>>(ghist, ctrl);
    mfma_filter<<<dim3(64, 64), 256, 0, stream>>>(Xsb, Xob, ctrl, cidx);
    refine_kernel<<<CAP / 4, 256, 0, stream>>>(ctrl, cidx, Xs64, Xo64, cval);
    rank_count<<<dim3(CAP / 256, JSLICES), 256, 0, stream>>>(ctrl, cval, cidx, rank);
    rank_scatter<<<CAP / 256, 256, 0, stream>>>(ctrl, cval, cidx, rank, svalv, sidxv);
    nms_prep<<<(TOPK + 255) / 256, 256, 0, stream>>>(sidxv, rois, ub);
    nms_kernel<<<dim3((TOPK + 255) / 256, (TOPK + 255) / 256), 256, 0, stream>>>(ub, sup);
    finalize_kernel<<<1, 1024, 0, stream>>>(sup, svalv, sidxv, (float*)d_out);
}

// Round 7
// 340.099 us; speedup vs baseline: 3.2130x; 1.2081x over previous
//
#include <hip/hip_runtime.h>
#include <math.h>

// Problem constants
#define NB    8192          // N
#define FEAT  255
#define HID   64
#define TOPK  6000
#define POSTK 300
#define BINS  8192          // 13-bit sortable-float key bins (sign+8exp+4mant)
#define BSHIFT 19           // 32-13
#define CAP   131072        // candidate buffer capacity
#define CAPLIM 98304        // target upper bound on estimated candidate count
#define SLACK 1             // bins below bstar (bf16-mfma vs f64 err 0.03 << bin 0.5)
#define TSEL  1000          // sampled cnt_ge target (1/8 col sample => true >= 6000 at +9.7 sigma)
#define JSLICES 64          // j-dimension parallelism for rank counting
#define LCAP  2048          // per-block LDS candidate buffer (overflow -> direct atomic)

typedef __attribute__((ext_vector_type(8))) short bf16x8;
typedef __attribute__((ext_vector_type(4))) float f32x4;

__device__ __forceinline__ unsigned binOf(float x) {
    unsigned u = __float_as_uint(x);
    u = (u & 0x80000000u) ? ~u : (u | 0x80000000u);   // sortable key (ascending)
    return u >> BSHIFT;
}

__device__ __forceinline__ unsigned short f2bf(float f) {   // RNE bf16 (finite inputs)
    unsigned u = __float_as_uint(f);
    return (unsigned short)((u + 0x7fffu + ((u >> 16) & 1u)) >> 16);
}

// ---------------------------------------------------------------------------
// K1: the two 255->64->64 MLPs in f64. One block = 4 rows, 64 threads/row.
// Writes row-major f64 (refine path) and row-major bf16 [n][64] (MFMA path).
// ---------------------------------------------------------------------------
__global__ __launch_bounds__(256) void mlp_kernel(
    const float* __restrict__ feat,
    const float* __restrict__ W1s, const float* __restrict__ b1s,
    const float* __restrict__ W2s, const float* __restrict__ b2s,
    const float* __restrict__ W1o, const float* __restrict__ b1o,
    const float* __restrict__ W2o, const float* __restrict__ b2o,
    double* __restrict__ Xs64, double* __restrict__ Xo64,
    unsigned short* __restrict__ Xsb, unsigned short* __restrict__ Xob)
{
    int tid  = threadIdx.x;
    int trow = tid >> 6;          // 0..3
    int t    = tid & 63;          // hidden unit
    int r    = blockIdx.x * 4 + trow;
    __shared__ double hs[4][64];
    __shared__ double ho[4][64];

    const float* frow = feat + (size_t)r * FEAT;
    double as = (double)b1s[t];
    double ao = (double)b1o[t];
    for (int k = 0; k < FEAT; ++k) {
        double fv = (double)frow[k];
        as += fv * (double)W1s[k * HID + t];
        ao += fv * (double)W1o[k * HID + t];
    }
    hs[trow][t] = as > 0.0 ? as : 0.0;
    ho[trow][t] = ao > 0.0 ? ao : 0.0;
    __syncthreads();

    double xs = (double)b2s[t];
    double xo = (double)b2o[t];
    for (int k = 0; k < HID; ++k) {
        xs += hs[trow][k] * (double)W2s[k * HID + t];
        xo += ho[trow][k] * (double)W2o[k * HID + t];
    }
    size_t o = (size_t)r * HID + t;
    Xs64[o] = xs;
    Xo64[o] = xo;
    Xsb[o] = f2bf((float)xs);
    Xob[o] = f2bf((float)xo);
}

// ---------------------------------------------------------------------------
// MFMA core: one block = 128x128 tile, 4 waves in 2x2, each wave 64x64 via
// 4x4 grid of 16x16x32 bf16 MFMAs over K=64 (2 k-chunks). Fragments load
// 16B of contiguous k directly from row-major bf16 [n][64] arrays.
// C/D layout (m89-verified): col=lane&15, row=quad*4+reg.
// ---------------------------------------------------------------------------
#define MFMA_COMPUTE(ACC)                                                     \
    f32x4 ACC[4][4];                                                          \
    _Pragma("unroll")                                                         \
    for (int ti = 0; ti < 4; ++ti)                                            \
        _Pragma("unroll")                                                     \
        for (int tj = 0; tj < 4; ++tj) ACC[ti][tj] = (f32x4){0,0,0,0};        \
    _Pragma("unroll")                                                         \
    for (int kc = 0; kc < 2; ++kc) {                                          \
        bf16x8 afr[4], bfr[4];                                                \
        _Pragma("unroll")                                                     \
        for (int t = 0; t < 4; ++t) {                                         \
            afr[t] = *(const bf16x8*)(Xsb + (size_t)(r0 + t * 16 + l16) * HID \
                                      + kc * 32 + quad * 8);                  \
            bfr[t] = *(const bf16x8*)(Xob + (size_t)(c0 + t * 16 + l16) * HID \
                                      + kc * 32 + quad * 8);                  \
        }                                                                     \
        _Pragma("unroll")                                                     \
        for (int ti = 0; ti < 4; ++ti)                                        \
            _Pragma("unroll")                                                 \
            for (int tj = 0; tj < 4; ++tj)                                    \
                ACC[ti][tj] = __builtin_amdgcn_mfma_f32_16x16x32_bf16(        \
                    afr[ti], bfr[tj], ACC[ti][tj], 0, 0, 0);                  \
    }

// ---------------------------------------------------------------------------
// K2: histogram pass over the 1/8 column sample (cols 0..1023).
// ---------------------------------------------------------------------------
__global__ __launch_bounds__(256) void mfma_hist(
    const unsigned short* __restrict__ Xsb, const unsigned short* __restrict__ Xob,
    unsigned* __restrict__ ghist)
{
    __shared__ unsigned hist[BINS];   // 32 KB
    int tid = threadIdx.x;
    for (int i = tid; i < BINS; i += 256) hist[i] = 0u;
    __syncthreads();

    int lane = tid & 63;
    int wave = tid >> 6;
    int quad = lane >> 4;
    int l16  = lane & 15;
    int r0 = blockIdx.y * 128 + (wave >> 1) * 64;
    int c0 = blockIdx.x * 128 + (wave & 1) * 64;   // gridDim.x = 8 -> cols 0..1023

    MFMA_COMPUTE(acc)

#pragma unroll
    for (int ti = 0; ti < 4; ++ti)
#pragma unroll
        for (int tj = 0; tj < 4; ++tj)
#pragma unroll
            for (int i = 0; i < 4; ++i) {
                int r = r0 + ti * 16 + quad * 4 + i;
                int c = c0 + tj * 16 + l16;
                float v = acc[ti][tj][i];
                if (r == c) v = -1.0f;
                atomicAdd(&hist[binOf(v)], 1u);
            }

    __syncthreads();
    for (int i = tid; i < BINS; i += 256) {
        unsigned h = hist[i];
        if (h) atomicAdd(&ghist[i], h);
    }
}

// ---------------------------------------------------------------------------
// K3: from the SAMPLED histogram find bstar = largest bin with
// cnt_ge >= TSEL, lower by SLACK, walk up while x8 estimate exceeds CAPLIM.
// ---------------------------------------------------------------------------
__global__ __launch_bounds__(256) void find_threshold(
    const unsigned* __restrict__ ghist, unsigned* __restrict__ ctrl)
{
    __shared__ unsigned csum[256];
    int tid  = threadIdx.x;
    int base = tid * (BINS / 256);
    unsigned s = 0;
    for (int i = 0; i < BINS / 256; ++i) s += ghist[base + i];
    csum[tid] = s;
    __syncthreads();
    if (tid == 0) {                       // suffix sums of chunk totals
        unsigned run = 0;
        for (int c = 255; c >= 0; --c) { run += csum[c]; csum[c] = run; }
    }
    __syncthreads();

    unsigned above = (tid == 255) ? 0u : csum[tid + 1];  // cnt_ge[chunk end]
    unsigned prev = above;
    for (int b = base + BINS / 256 - 1; b >= base; --b) {
        unsigned cur = prev + ghist[b];
        if (cur >= TSEL && prev < TSEL) {
            unsigned bstar = (unsigned)b;
            unsigned bt = bstar >= SLACK ? bstar - SLACK : 0;
            unsigned cnt = cur;
            for (unsigned bb = bstar; bb-- > bt;) cnt += ghist[bb];
            while (8u * cnt > CAPLIM && bt < bstar) { cnt -= ghist[bt]; bt++; }
            ctrl[1] = bt;
            break;
        }
        prev = cur;
    }
}

// ---------------------------------------------------------------------------
// K4: filter pass over the full matrix. Candidates are compacted into an
// LDS buffer via LDS atomics (fast, per-CU), then flushed with ONE global
// atomicAdd per block + coalesced stores. Overflow beyond LCAP falls back
// to direct global atomics (correctness preserved; order is irrelevant for
// rank-by-counting).
// ---------------------------------------------------------------------------
__global__ __launch_bounds__(256) void mfma_filter(
    const unsigned short* __restrict__ Xsb, const unsigned short* __restrict__ Xob,
    unsigned* __restrict__ ctrl, unsigned* __restrict__ cidx)
{
    __shared__ unsigned lcnt;
    __shared__ unsigned gbase;
    __shared__ unsigned lbuf[LCAP];   // 8 KB
    unsigned bt = ctrl[1];
    int tid = threadIdx.x;
    if (tid == 0) lcnt = 0;

    int lane = tid & 63;
    int wave = tid >> 6;
    int quad = lane >> 4;
    int l16  = lane & 15;
    int r0 = blockIdx.y * 128 + (wave >> 1) * 64;
    int c0 = blockIdx.x * 128 + (wave & 1) * 64;

    MFMA_COMPUTE(acc)

    __syncthreads();   // lcnt=0 visible (MFMA section has no block sync)

#pragma unroll
    for (int ti = 0; ti < 4; ++ti)
#pragma unroll
        for (int tj = 0; tj < 4; ++tj)
#pragma unroll
            for (int i = 0; i < 4; ++i) {
                int r = r0 + ti * 16 + quad * 4 + i;
                int c = c0 + tj * 16 + l16;
                float v = acc[ti][tj][i];
                if (r == c) v = -1.0f;
                if (binOf(v) >= bt) {
                    unsigned rc = (unsigned)r * (unsigned)NB + (unsigned)c;
                    unsigned p = atomicAdd(&lcnt, 1u);
                    if (p < LCAP) {
                        lbuf[p] = rc;
                    } else {             // overflow fallback (never in practice)
                        unsigned g = atomicAdd(&ctrl[0], 1u);
                        if (g < CAP) cidx[g] = rc;
                    }
                }
            }

    __syncthreads();
    unsigned n = lcnt; if (n > LCAP) n = LCAP;
    if (tid == 0 && n) gbase = atomicAdd(&ctrl[0], n);
    __syncthreads();
    for (unsigned i = tid; i < n; i += 256u) {
        unsigned p = gbase + i;
        if (p < CAP) cidx[p] = lbuf[i];
    }
}

// ---------------------------------------------------------------------------
// K4b: refine — one wave per candidate: 64 coalesced f64 loads, product,
// butterfly reduce (deterministic order; f64 noise 1e-15 << 1e-5 rank gaps).
// ---------------------------------------------------------------------------
__global__ __launch_bounds__(256) void refine_kernel(
    const unsigned* __restrict__ ctrl, const unsigned* __restrict__ cidx,
    const double* __restrict__ Xs64, const double* __restrict__ Xo64,
    double* __restrict__ cval)
{
    unsigned M = ctrl[0];
    if (M > CAP) M = CAP;
    unsigned w = blockIdx.x * 4u + (threadIdx.x >> 6);
    if (w >= M) return;
    int lane = threadIdx.x & 63;
    unsigned id = cidx[w];
    unsigned r = id >> 13, c = id & (NB - 1);
    double p = Xs64[(size_t)r * HID + lane] * Xo64[(size_t)c * HID + lane];
#pragma unroll
    for (int s = 32; s > 0; s >>= 1) p += __shfl_xor(p, s);
    if (lane == 0) cval[w] = (r == c) ? -1.0 : p;
}

// ---------------------------------------------------------------------------
// K5a: rank-by-counting, 2-D parallel. Composite key: value desc, flat
// index asc (jax top_k tie-break).
// ---------------------------------------------------------------------------
__global__ __launch_bounds__(256) void rank_count(
    const unsigned* __restrict__ ctrl,
    const double* __restrict__ cval, const unsigned* __restrict__ cidx,
    unsigned* __restrict__ rank)
{
    unsigned M = ctrl[0];
    if (M > CAP) M = CAP;
    unsigned itile = blockIdx.x;
    if (itile * 256u >= M) return;

    unsigned t = itile * 256u + threadIdx.x;
    bool act = t < M;
    double v  = act ? cval[t] : 0.0;
    unsigned id = act ? cidx[t] : 0u;
    unsigned cnt = 0;

    unsigned slice = blockIdx.y;
    unsigned jbeg = (unsigned)(((unsigned long long)slice * M) / JSLICES);
    unsigned jend = (unsigned)(((unsigned long long)(slice + 1) * M) / JSLICES);

    __shared__ double  lv[256];
    __shared__ unsigned li[256];
    for (unsigned base = jbeg; base < jend; base += 256u) {
        unsigned j = base + threadIdx.x;
        if (j < jend) { lv[threadIdx.x] = cval[j]; li[threadIdx.x] = cidx[j]; }
        __syncthreads();
        unsigned lim = jend - base; if (lim > 256u) lim = 256u;
        if (act) {
            for (unsigned e = 0; e < lim; ++e) {
                double ev = lv[e];
                cnt += (ev > v) || (ev == v && li[e] < id);
            }
        }
        __syncthreads();
    }
    if (act && cnt) atomicAdd(&rank[t], cnt);
}

// ---------------------------------------------------------------------------
// K5b: scatter candidates with rank < TOPK into sorted arrays.
// ---------------------------------------------------------------------------
__global__ __launch_bounds__(256) void rank_scatter(
    const unsigned* __restrict__ ctrl,
    const double* __restrict__ cval, const unsigned* __restrict__ cidx,
    const unsigned* __restrict__ rank,
    double* __restrict__ sval, unsigned* __restrict__ sidx)
{
    unsigned M = ctrl[0];
    if (M > CAP) M = CAP;
    unsigned t = blockIdx.x * 256u + threadIdx.x;
    if (t >= M) return;
    unsigned r = rank[t];
    if (r < TOPK) { sval[r] = cval[t]; sidx[r] = cidx[t]; }
}

// ---------------------------------------------------------------------------
// K6: union boxes + 0.7*area for the sorted TOPK pairs.
// ---------------------------------------------------------------------------
__global__ __launch_bounds__(256) void nms_prep(
    const unsigned* __restrict__ sidx, const float* __restrict__ rois,
    double* __restrict__ ub)
{
    int t = blockIdx.x * 256 + threadIdx.x;
    if (t >= TOPK) return;
    unsigned id = sidx[t];
    unsigned s = id >> 13, o = id & (NB - 1);
    const float* bs = rois + (size_t)s * 5;
    const float* bo = rois + (size_t)o * 5;
    double x1 = fmin((double)bs[1], (double)bo[1]);
    double y1 = fmin((double)bs[2], (double)bo[2]);
    double x2 = fmax((double)bs[3], (double)bo[3]);
    double y2 = fmax((double)bs[4], (double)bo[4]);
    double area = (x2 - x1) * (y2 - y1);
    double* u = ub + (size_t)t * 5;
    u[0] = x1; u[1] = y1; u[2] = x2; u[3] = y2; u[4] = 0.7 * area;
}

// ---------------------------------------------------------------------------
// K7: suppressed[j] = OR_{i<j} (iou > 0.7). Division-free equivalent:
// inter/(ai+aj-inter+1e-8) > 0.7  <=>  1.7*inter > 0.7*ai + 0.7*aj + 7e-9.
// ---------------------------------------------------------------------------
__global__ __launch_bounds__(256) void nms_kernel(
    const double* __restrict__ ub, unsigned* __restrict__ sup)
{
    int jb = blockIdx.x, ib = blockIdx.y;
    if (ib > jb) return;
    __shared__ double L[256][5];
    int tid = threadIdx.x;
    int ibase = ib * 256;
    int icount = TOPK - ibase; if (icount > 256) icount = 256;
    if (tid < icount) {
        const double* u = ub + (size_t)(ibase + tid) * 5;
#pragma unroll
        for (int q = 0; q < 5; ++q) L[tid][q] = u[q];
    }
    __syncthreads();

    int j = jb * 256 + tid;
    if (j >= TOPK) return;
    const double* u = ub + (size_t)j * 5;
    double x1 = u[0], y1 = u[1], x2 = u[2], y2 = u[3], pa = u[4];
    int lim = j - ibase; if (lim > icount) lim = icount;  // i < j
    bool flag = false;
    for (int e = 0; e < lim; ++e) {
        double ix1 = fmax(L[e][0], x1);
        double iy1 = fmax(L[e][1], y1);
        double ix2 = fmin(L[e][2], x2);
        double iy2 = fmin(L[e][3], y2);
        double iw = ix2 - ix1; iw = iw > 0.0 ? iw : 0.0;
        double ih = iy2 - iy1; ih = ih > 0.0 ? ih : 0.0;
        double inter = iw * ih;
        if (1.7 * inter > pa + L[e][4] + 7e-9) { flag = true; break; }
    }
    if (flag) atomicOr(&sup[j], 1u);
}

// ---------------------------------------------------------------------------
// K8: top-300 of where(sup,-1,score) over the descending-sorted list is a
// stable partition (unsuppressed first, then suppressed with score -1).
// Single block, chunked LDS scan. Writes all 900 output floats.
// ---------------------------------------------------------------------------
__global__ __launch_bounds__(1024) void finalize_kernel(
    const unsigned* __restrict__ sup, const double* __restrict__ sval,
    const unsigned* __restrict__ sidx, float* __restrict__ out)
{
    __shared__ unsigned pref[1024];
    __shared__ unsigned bases[2];   // running {unsup, sup} counts
    __shared__ unsigned totalu;
    int tid = threadIdx.x;

    unsigned s = 0;
    for (int i = tid; i < TOPK; i += 1024) s += (sup[i] == 0u);
    pref[tid] = s;
    __syncthreads();
    for (int st = 512; st > 0; st >>= 1) {
        if (tid < st) pref[tid] += pref[tid + st];
        __syncthreads();
    }
    if (tid == 0) { totalu = pref[0]; bases[0] = 0; bases[1] = 0; }
    __syncthreads();

    for (int c = 0; c < (TOPK + 1023) / 1024; ++c) {
        int idx = c * 1024 + tid;
        int valid = TOPK - c * 1024; if (valid > 1024) valid = 1024;
        unsigned f = (idx < TOPK && sup[idx] == 0u) ? 1u : 0u;
        pref[tid] = f;
        __syncthreads();
        for (int st = 1; st < 1024; st <<= 1) {
            unsigned add = (tid >= st) ? pref[tid - st] : 0u;
            __syncthreads();
            pref[tid] += add;
            __syncthreads();
        }
        if (idx < TOPK) {
            unsigned incl = pref[tid];
            unsigned e = incl - f;                     // unsup before me in chunk
            unsigned pos = f ? (bases[0] + e)
                             : (totalu + bases[1] + (unsigned)tid - e);
            if (pos < POSTK) {
                unsigned id = sidx[idx];
                unsigned sb = id >> 13, ob = id & (NB - 1);
                out[2 * pos]     = (float)sb;
                out[2 * pos + 1] = (float)ob;
                double sg = f ? 1.0 / (1.0 + exp(-sval[idx])) : -1.0;
                out[2 * POSTK + pos] = (float)sg;
            }
        }
        __syncthreads();
        if (tid == 0) {
            unsigned inclLast = pref[valid - 1];
            bases[0] += inclLast;
            bases[1] += (unsigned)valid - inclLast;
        }
        __syncthreads();
    }
}

// ---------------------------------------------------------------------------
extern "C" void kernel_launch(void* const* d_in, const int* in_sizes, int n_in,
                              void* d_out, int out_size, void* d_ws, size_t ws_size,
                              hipStream_t stream)
{
    const float* rois = (const float*)d_in[0];
    const float* feat = (const float*)d_in[1];
    const float* W1s  = (const float*)d_in[2];
    const float* b1s  = (const float*)d_in[3];
    const float* W2s  = (const float*)d_in[4];
    const float* b2s  = (const float*)d_in[5];
    const float* W1o  = (const float*)d_in[6];
    const float* b1o  = (const float*)d_in[7];
    const float* W2o  = (const float*)d_in[8];
    const float* b2o  = (const float*)d_in[9];

    char* ws = (char*)d_ws;
    size_t off = 0;
    auto alloc = [&](size_t bytes) -> void* {
        off = (off + 255) & ~(size_t)255;
        void* p = ws + off;
        off += bytes;
        return p;
    };

    // zeroed region first
    unsigned* ghist = (unsigned*)alloc((size_t)BINS * 4);     // histogram
    unsigned* ctrl  = (unsigned*)alloc(256);                  // [0]=cand count, [1]=bin threshold
    unsigned* sup   = (unsigned*)alloc((size_t)6144 * 4);     // suppression flags
    unsigned* rank  = (unsigned*)alloc((size_t)CAP * 4);      // candidate ranks
    size_t zero_bytes = off;

    double* Xs64 = (double*)alloc((size_t)NB * HID * 8);
    double* Xo64 = (double*)alloc((size_t)NB * HID * 8);
    unsigned short* Xsb = (unsigned short*)alloc((size_t)NB * HID * 2);
    unsigned short* Xob = (unsigned short*)alloc((size_t)NB * HID * 2);
    double* cval = (double*)alloc((size_t)CAP * 8);
    unsigned* cidx = (unsigned*)alloc((size_t)CAP * 4);
    double* svalv = (double*)alloc((size_t)TOPK * 8);
    unsigned* sidxv = (unsigned*)alloc((size_t)TOPK * 4);
    double* ub   = (double*)alloc((size_t)TOPK * 5 * 8);

    hipMemsetAsync(d_ws, 0, zero_bytes, stream);

    mlp_kernel<<<NB / 4, 256, 0, stream>>>(feat, W1s, b1s, W2s, b2s,
                                           W1o, b1o, W2o, b2o,
                                           Xs64, Xo64, Xsb, Xob);
    mfma_hist<<<dim3(8, 64), 256, 0, stream>>>(Xsb, Xob, ghist);
    find_threshold<<<1, 256, 0, stream>>>(ghist, ctrl);
    mfma_filter<<<dim3(64, 64), 256, 0, stream>>>(Xsb, Xob, ctrl, cidx);
    refine_kernel<<<CAP / 4, 256, 0, stream>>>(ctrl, cidx, Xs64, Xo64, cval);
    rank_count<<<dim3(CAP / 256, JSLICES), 256, 0, stream>>>(ctrl, cval, cidx, rank);
    rank_scatter<<<CAP / 256, 256, 0, stream>>>(ctrl, cval, cidx, rank, svalv, sidxv);
    nms_prep<<<(TOPK + 255) / 256, 256, 0, stream>>>(sidxv, rois, ub);
    nms_kernel<<<dim3((TOPK + 255) / 256, (TOPK + 255) / 256), 256, 0, stream>>>(ub, sup);
    finalize_kernel<<<1, 1024, 0, stream>>>(sup, svalv, sidxv, (float*)d_out);
}

// Round 8
// 328.730 us; speedup vs baseline: 3.3242x; 1.0346x over previous
//
#include <hip/hip_runtime.h>
#include <math.h>

// Problem constants
#define NB    8192          // N
#define FEAT  255
#define HID   64
#define TOPK  6000
#define POSTK 300
#define BINS  8192          // 13-bit sortable-float key bins (sign+8exp+4mant)
#define BSHIFT 19           // 32-13
#define CAP   131072        // candidate buffer capacity
#define CAPLIM 98304        // target upper bound on estimated candidate count
#define SLACK 1             // bins below bstar (bf16-mfma vs f64 err 0.03 << bin 0.5)
#define TSEL  1000          // sampled cnt_ge target (1/8 col sample => true >= 6000 at +9.7 sigma)
#define JSLICES 64          // j-dimension parallelism for rank counting
#define LCAP  2048          // per-block LDS candidate buffer (overflow -> direct atomic)
#define LSTRIDE 72          // LDS tile row stride in shorts (64 + 8 pad; 16B-aligned rows)

typedef __attribute__((ext_vector_type(8))) short bf16x8;
typedef __attribute__((ext_vector_type(4))) float f32x4;

__device__ __forceinline__ unsigned binOf(float x) {
    unsigned u = __float_as_uint(x);
    u = (u & 0x80000000u) ? ~u : (u | 0x80000000u);   // sortable key (ascending)
    return u >> BSHIFT;
}

__device__ __forceinline__ unsigned short f2bf(float f) {   // RNE bf16 (finite inputs)
    unsigned u = __float_as_uint(f);
    return (unsigned short)((u + 0x7fffu + ((u >> 16) & 1u)) >> 16);
}

// ---------------------------------------------------------------------------
// K1: the two 255->64->64 MLPs in f64, 4 independent accumulators per chain
// (breaks the serial FMA dependency; deterministic pairwise merge).
// One block = 4 rows, 64 threads/row. Writes f64 (refine) + bf16 (MFMA).
// ---------------------------------------------------------------------------
__global__ __launch_bounds__(256) void mlp_kernel(
    const float* __restrict__ feat,
    const float* __restrict__ W1s, const float* __restrict__ b1s,
    const float* __restrict__ W2s, const float* __restrict__ b2s,
    const float* __restrict__ W1o, const float* __restrict__ b1o,
    const float* __restrict__ W2o, const float* __restrict__ b2o,
    double* __restrict__ Xs64, double* __restrict__ Xo64,
    unsigned short* __restrict__ Xsb, unsigned short* __restrict__ Xob)
{
    int tid  = threadIdx.x;
    int trow = tid >> 6;          // 0..3
    int t    = tid & 63;          // hidden unit
    int r    = blockIdx.x * 4 + trow;
    __shared__ double hs[4][64];
    __shared__ double ho[4][64];

    const float* frow = feat + (size_t)r * FEAT;
    double a0 = 0, a1 = 0, a2 = 0, a3 = 0;
    double o0 = 0, o1 = 0, o2 = 0, o3 = 0;
    for (int k = 0; k < 252; k += 4) {
        double f0 = (double)frow[k],     f1 = (double)frow[k + 1];
        double f2 = (double)frow[k + 2], f3 = (double)frow[k + 3];
        a0 += f0 * (double)W1s[(k    ) * HID + t];
        a1 += f1 * (double)W1s[(k + 1) * HID + t];
        a2 += f2 * (double)W1s[(k + 2) * HID + t];
        a3 += f3 * (double)W1s[(k + 3) * HID + t];
        o0 += f0 * (double)W1o[(k    ) * HID + t];
        o1 += f1 * (double)W1o[(k + 1) * HID + t];
        o2 += f2 * (double)W1o[(k + 2) * HID + t];
        o3 += f3 * (double)W1o[(k + 3) * HID + t];
    }
    double as = (double)b1s[t] + ((a0 + a1) + (a2 + a3));
    double ao = (double)b1o[t] + ((o0 + o1) + (o2 + o3));
    for (int k = 252; k < FEAT; ++k) {
        double fv = (double)frow[k];
        as += fv * (double)W1s[k * HID + t];
        ao += fv * (double)W1o[k * HID + t];
    }
    hs[trow][t] = as > 0.0 ? as : 0.0;
    ho[trow][t] = ao > 0.0 ? ao : 0.0;
    __syncthreads();

    double c0 = 0, c1 = 0, c2 = 0, c3 = 0;
    double d0 = 0, d1 = 0, d2 = 0, d3 = 0;
    for (int k = 0; k < HID; k += 4) {
        double h0 = hs[trow][k],     h1 = hs[trow][k + 1];
        double h2 = hs[trow][k + 2], h3 = hs[trow][k + 3];
        double g0 = ho[trow][k],     g1 = ho[trow][k + 1];
        double g2 = ho[trow][k + 2], g3 = ho[trow][k + 3];
        c0 += h0 * (double)W2s[(k    ) * HID + t];
        c1 += h1 * (double)W2s[(k + 1) * HID + t];
        c2 += h2 * (double)W2s[(k + 2) * HID + t];
        c3 += h3 * (double)W2s[(k + 3) * HID + t];
        d0 += g0 * (double)W2o[(k    ) * HID + t];
        d1 += g1 * (double)W2o[(k + 1) * HID + t];
        d2 += g2 * (double)W2o[(k + 2) * HID + t];
        d3 += g3 * (double)W2o[(k + 3) * HID + t];
    }
    double xs = (double)b2s[t] + ((c0 + c1) + (c2 + c3));
    double xo = (double)b2o[t] + ((d0 + d1) + (d2 + d3));

    size_t o = (size_t)r * HID + t;
    Xs64[o] = xs;
    Xo64[o] = xo;
    Xsb[o] = f2bf((float)xs);
    Xob[o] = f2bf((float)xo);
}

// ---------------------------------------------------------------------------
// Staged MFMA core: block stages its 128-row A slab and 128-row B slab in
// LDS (coalesced uint4 bulk load, padded rows), then each of 4 waves (2x2)
// computes a 64x64 tile via 4x4 grid of 16x16x32 bf16 MFMAs over K=64.
// C/D layout (m89-verified): col=lane&15, row=quad*4+reg.
// ---------------------------------------------------------------------------
#define STAGE_TILES(AsArr, BsArr, r0base, c0base)                             \
    for (int i = tid; i < 1024; i += 256) {                                   \
        int row = i >> 3, ch = i & 7;                                         \
        *(uint4*)&AsArr[row * LSTRIDE + ch * 8] =                             \
            *(const uint4*)(Xsb + (size_t)(r0base + row) * HID + ch * 8);     \
        *(uint4*)&BsArr[row * LSTRIDE + ch * 8] =                             \
            *(const uint4*)(Xob + (size_t)(c0base + row) * HID + ch * 8);     \
    }                                                                         \
    __syncthreads();

#define MFMA_LDS(ACC, AsArr, BsArr)                                           \
    f32x4 ACC[4][4];                                                          \
    _Pragma("unroll")                                                         \
    for (int ti = 0; ti < 4; ++ti)                                            \
        _Pragma("unroll")                                                     \
        for (int tj = 0; tj < 4; ++tj) ACC[ti][tj] = (f32x4){0,0,0,0};        \
    {                                                                         \
        int awr = (wave >> 1) * 64 + l16;                                     \
        int bwr = (wave & 1) * 64 + l16;                                      \
        _Pragma("unroll")                                                     \
        for (int kc = 0; kc < 2; ++kc) {                                      \
            bf16x8 afr[4], bfr[4];                                            \
            _Pragma("unroll")                                                 \
            for (int t = 0; t < 4; ++t) {                                     \
                afr[t] = *(const bf16x8*)&AsArr[(awr + t * 16) * LSTRIDE      \
                                                + kc * 32 + quad * 8];        \
                bfr[t] = *(const bf16x8*)&BsArr[(bwr + t * 16) * LSTRIDE      \
                                                + kc * 32 + quad * 8];        \
            }                                                                 \
            _Pragma("unroll")                                                 \
            for (int ti = 0; ti < 4; ++ti)                                    \
                _Pragma("unroll")                                             \
                for (int tj = 0; tj < 4; ++tj)                                \
                    ACC[ti][tj] = __builtin_amdgcn_mfma_f32_16x16x32_bf16(    \
                        afr[ti], bfr[tj], ACC[ti][tj], 0, 0, 0);              \
        }                                                                     \
    }

// ---------------------------------------------------------------------------
// K2: histogram pass over the 1/8 column sample (cols 0..1023).
// ---------------------------------------------------------------------------
__global__ __launch_bounds__(256) void mfma_hist(
    const unsigned short* __restrict__ Xsb, const unsigned short* __restrict__ Xob,
    unsigned* __restrict__ ghist)
{
    __shared__ unsigned hist[BINS];                   // 32 KB
    __shared__ unsigned short As[128 * LSTRIDE];      // 18 KB
    __shared__ unsigned short Bs[128 * LSTRIDE];      // 18 KB
    int tid = threadIdx.x;
    for (int i = tid; i < BINS; i += 256) hist[i] = 0u;

    int r0base = blockIdx.y * 128;
    int c0base = blockIdx.x * 128;    // gridDim.x = 8 -> cols 0..1023
    STAGE_TILES(As, Bs, r0base, c0base)

    int lane = tid & 63;
    int wave = tid >> 6;
    int quad = lane >> 4;
    int l16  = lane & 15;
    int r0 = r0base + (wave >> 1) * 64;
    int c0 = c0base + (wave & 1) * 64;

    MFMA_LDS(acc, As, Bs)

#pragma unroll
    for (int ti = 0; ti < 4; ++ti)
#pragma unroll
        for (int tj = 0; tj < 4; ++tj)
#pragma unroll
            for (int i = 0; i < 4; ++i) {
                int r = r0 + ti * 16 + quad * 4 + i;
                int c = c0 + tj * 16 + l16;
                float v = acc[ti][tj][i];
                if (r == c) v = -1.0f;
                atomicAdd(&hist[binOf(v)], 1u);
            }

    __syncthreads();
    for (int i = tid; i < BINS; i += 256) {
        unsigned h = hist[i];
        if (h) atomicAdd(&ghist[i], h);
    }
}

// ---------------------------------------------------------------------------
// K3: from the SAMPLED histogram find bstar = largest bin with
// cnt_ge >= TSEL, lower by SLACK, walk up while x8 estimate exceeds CAPLIM.
// ---------------------------------------------------------------------------
__global__ __launch_bounds__(256) void find_threshold(
    const unsigned* __restrict__ ghist, unsigned* __restrict__ ctrl)
{
    __shared__ unsigned csum[256];
    int tid  = threadIdx.x;
    int base = tid * (BINS / 256);
    unsigned s = 0;
    for (int i = 0; i < BINS / 256; ++i) s += ghist[base + i];
    csum[tid] = s;
    __syncthreads();
    if (tid == 0) {                       // suffix sums of chunk totals
        unsigned run = 0;
        for (int c = 255; c >= 0; --c) { run += csum[c]; csum[c] = run; }
    }
    __syncthreads();

    unsigned above = (tid == 255) ? 0u : csum[tid + 1];  // cnt_ge[chunk end]
    unsigned prev = above;
    for (int b = base + BINS / 256 - 1; b >= base; --b) {
        unsigned cur = prev + ghist[b];
        if (cur >= TSEL && prev < TSEL) {
            unsigned bstar = (unsigned)b;
            unsigned bt = bstar >= SLACK ? bstar - SLACK : 0;
            unsigned cnt = cur;
            for (unsigned bb = bstar; bb-- > bt;) cnt += ghist[bb];
            while (8u * cnt > CAPLIM && bt < bstar) { cnt -= ghist[bt]; bt++; }
            ctrl[1] = bt;
            break;
        }
        prev = cur;
    }
}

// ---------------------------------------------------------------------------
// K4: filter pass over the full matrix, LDS-staged tiles. Candidates are
// compacted into an LDS buffer via LDS atomics, then flushed with ONE
// global atomicAdd per block + coalesced stores. Overflow falls back to
// direct global atomics (order is irrelevant for rank-by-counting).
// ---------------------------------------------------------------------------
__global__ __launch_bounds__(256) void mfma_filter(
    const unsigned short* __restrict__ Xsb, const unsigned short* __restrict__ Xob,
    unsigned* __restrict__ ctrl, unsigned* __restrict__ cidx)
{
    __shared__ unsigned lcnt;
    __shared__ unsigned gbase;
    __shared__ unsigned lbuf[LCAP];                   // 8 KB
    __shared__ unsigned short As[128 * LSTRIDE];      // 18 KB
    __shared__ unsigned short Bs[128 * LSTRIDE];      // 18 KB
    unsigned bt = ctrl[1];
    int tid = threadIdx.x;
    if (tid == 0) lcnt = 0;

    int r0base = blockIdx.y * 128;
    int c0base = blockIdx.x * 128;
    STAGE_TILES(As, Bs, r0base, c0base)   // sync also makes lcnt=0 visible

    int lane = tid & 63;
    int wave = tid >> 6;
    int quad = lane >> 4;
    int l16  = lane & 15;
    int r0 = r0base + (wave >> 1) * 64;
    int c0 = c0base + (wave & 1) * 64;

    MFMA_LDS(acc, As, Bs)

#pragma unroll
    for (int ti = 0; ti < 4; ++ti)
#pragma unroll
        for (int tj = 0; tj < 4; ++tj)
#pragma unroll
            for (int i = 0; i < 4; ++i) {
                int r = r0 + ti * 16 + quad * 4 + i;
                int c = c0 + tj * 16 + l16;
                float v = acc[ti][tj][i];
                if (r == c) v = -1.0f;
                if (binOf(v) >= bt) {
                    unsigned rc = (unsigned)r * (unsigned)NB + (unsigned)c;
                    unsigned p = atomicAdd(&lcnt, 1u);
                    if (p < LCAP) {
                        lbuf[p] = rc;
                    } else {             // overflow fallback (never in practice)
                        unsigned g = atomicAdd(&ctrl[0], 1u);
                        if (g < CAP) cidx[g] = rc;
                    }
                }
            }

    __syncthreads();
    unsigned n = lcnt; if (n > LCAP) n = LCAP;
    if (tid == 0 && n) gbase = atomicAdd(&ctrl[0], n);
    __syncthreads();
    for (unsigned i = tid; i < n; i += 256u) {
        unsigned p = gbase + i;
        if (p < CAP) cidx[p] = lbuf[i];
    }
}

// ---------------------------------------------------------------------------
// K4b: refine — one wave per candidate (grid-stride): 64 coalesced f64
// loads, product, butterfly reduce (deterministic; 1e-15 << 1e-5 gaps).
// ---------------------------------------------------------------------------
__global__ __launch_bounds__(256) void refine_kernel(
    const unsigned* __restrict__ ctrl, const unsigned* __restrict__ cidx,
    const double* __restrict__ Xs64, const double* __restrict__ Xo64,
    double* __restrict__ cval)
{
    unsigned M = ctrl[0];
    if (M > CAP) M = CAP;
    unsigned nw = gridDim.x * 4u;
    int lane = threadIdx.x & 63;
    for (unsigned w = blockIdx.x * 4u + (threadIdx.x >> 6); w < M; w += nw) {
        unsigned id = cidx[w];
        unsigned r = id >> 13, c = id & (NB - 1);
        double p = Xs64[(size_t)r * HID + lane] * Xo64[(size_t)c * HID + lane];
#pragma unroll
        for (int s = 32; s > 0; s >>= 1) p += __shfl_xor(p, s);
        if (lane == 0) cval[w] = (r == c) ? -1.0 : p;
    }
}

// ---------------------------------------------------------------------------
// K5a: rank-by-counting, 2-D parallel (grid-stride i-tiles x j-slices).
// Composite key: value desc, flat index asc (jax top_k tie-break).
// ---------------------------------------------------------------------------
__global__ __launch_bounds__(256) void rank_count(
    const unsigned* __restrict__ ctrl,
    const double* __restrict__ cval, const unsigned* __restrict__ cidx,
    unsigned* __restrict__ rank)
{
    unsigned M = ctrl[0];
    if (M > CAP) M = CAP;

    unsigned slice = blockIdx.y;
    unsigned jbeg = (unsigned)(((unsigned long long)slice * M) / JSLICES);
    unsigned jend = (unsigned)(((unsigned long long)(slice + 1) * M) / JSLICES);

    __shared__ double  lv[256];
    __shared__ unsigned li[256];

    for (unsigned itile = blockIdx.x; itile * 256u < M; itile += gridDim.x) {
        unsigned t = itile * 256u + threadIdx.x;
        bool act = t < M;
        double v  = act ? cval[t] : 0.0;
        unsigned id = act ? cidx[t] : 0u;
        unsigned cnt = 0;

        for (unsigned base = jbeg; base < jend; base += 256u) {
            unsigned j = base + threadIdx.x;
            if (j < jend) { lv[threadIdx.x] = cval[j]; li[threadIdx.x] = cidx[j]; }
            __syncthreads();
            unsigned lim = jend - base; if (lim > 256u) lim = 256u;
            if (act) {
                for (unsigned e = 0; e < lim; ++e) {
                    double ev = lv[e];
                    cnt += (ev > v) || (ev == v && li[e] < id);
                }
            }
            __syncthreads();
        }
        if (act && cnt) atomicAdd(&rank[t], cnt);
    }
}

// ---------------------------------------------------------------------------
// K5b: scatter rank<TOPK candidates into sorted arrays AND build the NMS
// union boxes + 0.7*area in the same pass (fused former nms_prep).
// ---------------------------------------------------------------------------
__global__ __launch_bounds__(256) void rank_scatter_prep(
    const unsigned* __restrict__ ctrl,
    const double* __restrict__ cval, const unsigned* __restrict__ cidx,
    const unsigned* __restrict__ rank, const float* __restrict__ rois,
    double* __restrict__ sval, unsigned* __restrict__ sidx,
    double* __restrict__ ub)
{
    unsigned M = ctrl[0];
    if (M > CAP) M = CAP;
    unsigned stride = gridDim.x * 256u;
    for (unsigned t = blockIdx.x * 256u + threadIdx.x; t < M; t += stride) {
        unsigned rk = rank[t];
        if (rk < TOPK) {
            unsigned id = cidx[t];
            sval[rk] = cval[t];
            sidx[rk] = id;
            unsigned s = id >> 13, o = id & (NB - 1);
            const float* bs = rois + (size_t)s * 5;
            const float* bo = rois + (size_t)o * 5;
            double x1 = fmin((double)bs[1], (double)bo[1]);
            double y1 = fmin((double)bs[2], (double)bo[2]);
            double x2 = fmax((double)bs[3], (double)bo[3]);
            double y2 = fmax((double)bs[4], (double)bo[4]);
            double area = (x2 - x1) * (y2 - y1);
            double* u = ub + (size_t)rk * 5;
            u[0] = x1; u[1] = y1; u[2] = x2; u[3] = y2; u[4] = 0.7 * area;
        }
    }
}

// ---------------------------------------------------------------------------
// K7: suppressed[j] = OR_{i<j} (iou > 0.7). Division-free equivalent:
// inter/(ai+aj-inter+1e-8) > 0.7  <=>  1.7*inter > 0.7*ai + 0.7*aj + 7e-9.
// ---------------------------------------------------------------------------
__global__ __launch_bounds__(256) void nms_kernel(
    const double* __restrict__ ub, unsigned* __restrict__ sup)
{
    int jb = blockIdx.x, ib = blockIdx.y;
    if (ib > jb) return;
    __shared__ double L[256][5];
    int tid = threadIdx.x;
    int ibase = ib * 256;
    int icount = TOPK - ibase; if (icount > 256) icount = 256;
    if (tid < icount) {
        const double* u = ub + (size_t)(ibase + tid) * 5;
#pragma unroll
        for (int q = 0; q < 5; ++q) L[tid][q] = u[q];
    }
    __syncthreads();

    int j = jb * 256 + tid;
    if (j >= TOPK) return;
    const double* u = ub + (size_t)j * 5;
    double x1 = u[0], y1 = u[1], x2 = u[2], y2 = u[3], pa = u[4];
    int lim = j - ibase; if (lim > icount) lim = icount;  // i < j
    bool flag = false;
    for (int e = 0; e < lim; ++e) {
        double ix1 = fmax(L[e][0], x1);
        double iy1 = fmax(L[e][1], y1);
        double ix2 = fmin(L[e][2], x2);
        double iy2 = fmin(L[e][3], y2);
        double iw = ix2 - ix1; iw = iw > 0.0 ? iw : 0.0;
        double ih = iy2 - iy1; ih = ih > 0.0 ? ih : 0.0;
        double inter = iw * ih;
        if (1.7 * inter > pa + L[e][4] + 7e-9) { flag = true; break; }
    }
    if (flag) atomicOr(&sup[j], 1u);
}

// ---------------------------------------------------------------------------
// K8: top-300 of where(sup,-1,score) over the descending-sorted list is a
// stable partition (unsuppressed first, then suppressed with score -1).
// Single block, chunked LDS scan. Writes all 900 output floats.
// ---------------------------------------------------------------------------
__global__ __launch_bounds__(1024) void finalize_kernel(
    const unsigned* __restrict__ sup, const double* __restrict__ sval,
    const unsigned* __restrict__ sidx, float* __restrict__ out)
{
    __shared__ unsigned pref[1024];
    __shared__ unsigned bases[2];   // running {unsup, sup} counts
    __shared__ unsigned totalu;
    int tid = threadIdx.x;

    unsigned s = 0;
    for (int i = tid; i < TOPK; i += 1024) s += (sup[i] == 0u);
    pref[tid] = s;
    __syncthreads();
    for (int st = 512; st > 0; st >>= 1) {
        if (tid < st) pref[tid] += pref[tid + st];
        __syncthreads();
    }
    if (tid == 0) { totalu = pref[0]; bases[0] = 0; bases[1] = 0; }
    __syncthreads();

    for (int c = 0; c < (TOPK + 1023) / 1024; ++c) {
        int idx = c * 1024 + tid;
        int valid = TOPK - c * 1024; if (valid > 1024) valid = 1024;
        unsigned f = (idx < TOPK && sup[idx] == 0u) ? 1u : 0u;
        pref[tid] = f;
        __syncthreads();
        for (int st = 1; st < 1024; st <<= 1) {
            unsigned add = (tid >= st) ? pref[tid - st] : 0u;
            __syncthreads();
            pref[tid] += add;
            __syncthreads();
        }
        if (idx < TOPK) {
            unsigned incl = pref[tid];
            unsigned e = incl - f;                     // unsup before me in chunk
            unsigned pos = f ? (bases[0] + e)
                             : (totalu + bases[1] + (unsigned)tid - e);
            if (pos < POSTK) {
                unsigned id = sidx[idx];
                unsigned sb = id >> 13, ob = id & (NB - 1);
                out[2 * pos]     = (float)sb;
                out[2 * pos + 1] = (float)ob;
                double sg = f ? 1.0 / (1.0 + exp(-sval[idx])) : -1.0;
                out[2 * POSTK + pos] = (float)sg;
            }
        }
        __syncthreads();
        if (tid == 0) {
            unsigned inclLast = pref[valid - 1];
            bases[0] += inclLast;
            bases[1] += (unsigned)valid - inclLast;
        }
        __syncthreads();
    }
}

// ---------------------------------------------------------------------------
extern "C" void kernel_launch(void* const* d_in, const int* in_sizes, int n_in,
                              void* d_out, int out_size, void* d_ws, size_t ws_size,
                              hipStream_t stream)
{
    const float* rois = (const float*)d_in[0];
    const float* feat = (const float*)d_in[1];
    const float* W1s  = (const float*)d_in[2];
    const float* b1s  = (const float*)d_in[3];
    const float* W2s  = (const float*)d_in[4];
    const float* b2s  = (const float*)d_in[5];
    const float* W1o  = (const float*)d_in[6];
    const float* b1o  = (const float*)d_in[7];
    const float* W2o  = (const float*)d_in[8];
    const float* b2o  = (const float*)d_in[9];

    char* ws = (char*)d_ws;
    size_t off = 0;
    auto alloc = [&](size_t bytes) -> void* {
        off = (off + 255) & ~(size_t)255;
        void* p = ws + off;
        off += bytes;
        return p;
    };

    // zeroed region first
    unsigned* ghist = (unsigned*)alloc((size_t)BINS * 4);     // histogram
    unsigned* ctrl  = (unsigned*)alloc(256);                  // [0]=cand count, [1]=bin threshold
    unsigned* sup   = (unsigned*)alloc((size_t)6144 * 4);     // suppression flags
    unsigned* rank  = (unsigned*)alloc((size_t)CAP * 4);      // candidate ranks
    size_t zero_bytes = off;

    double* Xs64 = (double*)alloc((size_t)NB * HID * 8);
    double* Xo64 = (double*)alloc((size_t)NB * HID * 8);
    unsigned short* Xsb = (unsigned short*)alloc((size_t)NB * HID * 2);
    unsigned short* Xob = (unsigned short*)alloc((size_t)NB * HID * 2);
    double* cval = (double*)alloc((size_t)CAP * 8);
    unsigned* cidx = (unsigned*)alloc((size_t)CAP * 4);
    double* svalv = (double*)alloc((size_t)TOPK * 8);
    unsigned* sidxv = (unsigned*)alloc((size_t)TOPK * 4);
    double* ub   = (double*)alloc((size_t)TOPK * 5 * 8);

    hipMemsetAsync(d_ws, 0, zero_bytes, stream);

    mlp_kernel<<<NB / 4, 256, 0, stream>>>(feat, W1s, b1s, W2s, b2s,
                                           W1o, b1o, W2o, b2o,
                                           Xs64, Xo64, Xsb, Xob);
    mfma_hist<<<dim3(8, 64), 256, 0, stream>>>(Xsb, Xob, ghist);
    find_threshold<<<1, 256, 0, stream>>>(ghist, ctrl);
    mfma_filter<<<dim3(64, 64), 256, 0, stream>>>(Xsb, Xob, ctrl, cidx);
    refine_kernel<<<2048, 256, 0, stream>>>(ctrl, cidx, Xs64, Xo64, cval);
    rank_count<<<dim3(128, JSLICES), 256, 0, stream>>>(ctrl, cval, cidx, rank);
    rank_scatter_prep<<<512, 256, 0, stream>>>(ctrl, cval, cidx, rank, rois,
                                               svalv, sidxv, ub);
    nms_kernel<<<dim3((TOPK + 255) / 256, (TOPK + 255) / 256), 256, 0, stream>>>(ub, sup);
    finalize_kernel<<<1, 1024, 0, stream>>>(sup, svalv, sidxv, (float*)d_out);
}